// Round 8
// baseline (1412.930 us; speedup 1.0000x reference)
//
#include <hip/hip_runtime.h>
#include <hip/hip_bf16.h>

#define N_NODES   100000
#define N_EDGES   1600000
#define NUM_GRAPHS 1000

typedef unsigned int u32;
typedef unsigned short u16;

typedef __bf16 bf16_t;
typedef bf16_t bf16x8 __attribute__((ext_vector_type(8)));
typedef float  f32x4  __attribute__((ext_vector_type(4)));
typedef u32    u32x4  __attribute__((ext_vector_type(4)));

__device__ __forceinline__ float bf2f(u16 u){ return __uint_as_float(((u32)u)<<16); }
__device__ __forceinline__ float BL(u32 u){ return __uint_as_float(u<<16); }
__device__ __forceinline__ float BH(u32 u){ return __uint_as_float(u&0xffff0000u); }
// f32 -> bf16 bits, round-to-nearest-even
__device__ __forceinline__ u16 f2bf(float f){
  u32 u = __float_as_uint(f);
  return (u16)((u + 0x7fffu + ((u>>16)&1u)) >> 16);
}
// dual-dtype scalar load: isbf=1 -> bf16, else f32
__device__ __forceinline__ float ldf(const void* p, size_t i, int isbf){
  return isbf ? bf2f(((const u16*)p)[i]) : ((const float*)p)[i];
}
// non-temporal 16B load/store (streaming, keep out of L2/L3 hot set)
__device__ __forceinline__ uint4 ntload4(const void* p){
  u32x4 v = __builtin_nontemporal_load((const u32x4*)p);
  return make_uint4(v.x, v.y, v.z, v.w);
}
__device__ __forceinline__ void ntstore4(void* p, uint4 v){
  u32x4 t = {v.x, v.y, v.z, v.w};
  __builtin_nontemporal_store(t, (u32x4*)p);
}

union U4BF { uint4 u; bf16x8 v; };

// ---------------- dtype detector ----------------
__global__ void k_detect(const u32* __restrict__ x, int* __restrict__ flag){
  int t = threadIdx.x; int cnt = 0;
  for (int i = t; i < 256; i += 64){
    u32 w = x[i];
    u32 e = (w >> 7) & 0xffu;
    if (e >= 110u && e <= 137u) cnt++;
  }
  for (int o = 32; o; o >>= 1) cnt += __shfl_xor(cnt, o);
  if (t == 0) *flag = (cnt > 128) ? 1 : 0;
}

// ---------------- identity affine init: s=1, t=0 ----------------
__global__ void k_idaff(float* __restrict__ haff){
  int c = threadIdx.x;
  haff[c] = 1.f; haff[64 + c] = 0.f;
}

// ---------------- weight prep: base Weff[l][c][96] + f32 base bias ---------
__global__ void k_prep(const void* __restrict__ eW, const void* __restrict__ eb,
                       const void* __restrict__ mW, const void* __restrict__ mb,
                       u16* __restrict__ Weff, float* __restrict__ biasm,
                       const int* __restrict__ flagp){
  int isbf = *flagp;
  int l = blockIdx.x, c = threadIdx.x;
  u16* W = Weff + ((size_t)l*64 + c)*96;
  for (int k = 0; k < 64; k++)
    W[k] = f2bf(ldf(mW, (size_t)(l*96 + k)*64 + c, isbf));
  for (int j = 0; j < 16; j++){
    float acc = 0.f;
    for (int k = 0; k < 32; k++)
      acc += ldf(eW, (size_t)j*32 + k, isbf) * ldf(mW, (size_t)(l*96 + 64 + k)*64 + c, isbf);
    W[64 + j] = f2bf(acc);
  }
  float fbv = ldf(mb, (size_t)l*64 + c, isbf);
  for (int k = 0; k < 32; k++)
    fbv += ldf(eb, k, isbf) * ldf(mW, (size_t)(l*96 + 64 + k)*64 + c, isbf);
  W[80] = f2bf(fbv);
  biasm[(size_t)l*64 + c] = fbv;
  for (int k = 81; k < 96; k++) W[k] = 0;
}

// ---------------- per-layer msg-weight fold ----------------
__global__ void k_fold(const void* __restrict__ mW, const u16* __restrict__ Wbase,
                       const float* __restrict__ biasm, const float* __restrict__ haff,
                       u16* __restrict__ Wf, const int* __restrict__ flagp, int l){
  int isbf = *flagp; int c = threadIdx.x;
  const u16* Wb = Wbase + ((size_t)l*64 + c)*96;
  u16* W = Wf + (size_t)c*96;
  float bb = biasm[(size_t)l*64 + c];
  for (int k = 0; k < 64; k++){
    float w = ldf(mW, (size_t)(l*96 + k)*64 + c, isbf);
    W[k] = f2bf(haff[k] * w);
    bb = fmaf(haff[64 + k], w, bb);
  }
  for (int k = 64; k < 80; k++) W[k] = Wb[k];
  W[80] = f2bf(bb);
  for (int k = 81; k < 96; k++) W[k] = 0;
}

// ---------------- update-weight prep ----------------
__global__ void k_updprep(const void* __restrict__ uW, const void* __restrict__ ub,
                          const float* __restrict__ maff, const float* __restrict__ haff,
                          u16* __restrict__ Wupd, float* __restrict__ biasv,
                          float* __restrict__ tvv, const int* __restrict__ flagp, int l){
  int isbf = *flagp; int c = threadIdx.x;
  u16* W = Wupd + (size_t)c*192;
  float tv = 0.f, bb = 0.f;
  for (int k = 0; k < 64; k++){
    float wka = ldf(uW, (size_t)(l*128 + k)*64 + c, isbf);
    W[k] = f2bf(haff[k] * wka);
    bb = fmaf(haff[64 + k], wka, bb);
    float wkb = ldf(uW, (size_t)(l*128 + 64 + k)*64 + c, isbf);
    float prod = wkb * maff[k];
    u16 hi = f2bf(prod);
    W[64 + k]  = hi;
    W[128 + k] = f2bf(prod - bf2f(hi));
    tv = fmaf(maff[64 + k], wkb, tv);
  }
  biasv[c] = ldf(ub, (size_t)l*64 + c, isbf) + bb;
  tvv[c] = tv;
}

// ---------------- node embedding -> hsp split hi/lo ----
__global__ void k_node_emb(const void* __restrict__ x, const void* __restrict__ nW,
                           const void* __restrict__ nb, u16* __restrict__ hsp,
                           const int* __restrict__ flagp){
  int isbf = *flagp;
  int lane = threadIdx.x & 63;
  int gw = (blockIdx.x*blockDim.x + threadIdx.x) >> 6;
  int nw = (gridDim.x*blockDim.x) >> 6;
  float w[32];
#pragma unroll
  for (int k = 0; k < 32; k++) w[k] = ldf(nW, (size_t)k*64 + lane, isbf);
  float bias = ldf(nb, lane, isbf);
  for (int n = gw; n < N_NODES; n += nw){
    float acc = bias;
    if (isbf){
      const uint4* xr = (const uint4*)((const u16*)x + (size_t)n*32);
#pragma unroll
      for (int q = 0; q < 4; q++){
        uint4 a = xr[q];
        u32 uu[4] = {a.x, a.y, a.z, a.w};
#pragma unroll
        for (int j = 0; j < 4; j++){
          acc = fmaf(BL(uu[j]), w[q*8 + 2*j + 0], acc);
          acc = fmaf(BH(uu[j]), w[q*8 + 2*j + 1], acc);
        }
      }
    } else {
      const float4* xr = (const float4*)((const float*)x + (size_t)n*32);
#pragma unroll
      for (int q = 0; q < 8; q++){
        float4 a = xr[q];
        acc = fmaf(a.x, w[q*4+0], acc); acc = fmaf(a.y, w[q*4+1], acc);
        acc = fmaf(a.z, w[q*4+2], acc); acc = fmaf(a.w, w[q*4+3], acc);
      }
    }
    u16 hi = f2bf(acc);
    hsp[(size_t)n*128 + lane]      = hi;
    hsp[(size_t)n*128 + 64 + lane] = f2bf(acc - bf2f(hi));
  }
}

// ---------------- in-degree histogram ----------------
__global__ void k_deg(const int* __restrict__ ei, int* __restrict__ deg){
  int i = blockIdx.x*blockDim.x + threadIdx.x;
  int stride = gridDim.x*blockDim.x;
  for (int e = i; e < N_EDGES; e += stride)
    atomicAdd(&deg[ei[N_EDGES + e]], 1);
}

// ---------------- multi-block scan: phase 1 ----------------
__global__ void __launch_bounds__(256) k_scan1(const int* __restrict__ deg,
                                               int* __restrict__ bsum){
  __shared__ int wsum[4];
  int b = blockIdx.x, t = threadIdx.x;
  int i0 = b*512 + t;
  int s = 0;
  if (i0 < N_NODES) s += deg[i0];
  if (i0 + 256 < N_NODES) s += deg[i0 + 256];
  for (int o = 32; o; o >>= 1) s += __shfl_xor(s, o);
  if ((t & 63) == 0) wsum[t >> 6] = s;
  __syncthreads();
  if (t == 0) bsum[b] = wsum[0] + wsum[1] + wsum[2] + wsum[3];
}

// ---------------- scan phase 2 ----------------
__global__ void k_scan2(const int* __restrict__ bsum, int* __restrict__ boff,
                        int* __restrict__ rp){
  __shared__ int l[200];
  int t = threadIdx.x;
  if (t < 196) l[t] = bsum[t];
  __syncthreads();
  if (t == 0){
    int r = 0;
    for (int k = 0; k < 196; k++){ int x = l[k]; l[k] = r; r += x; }
    rp[N_NODES] = r;
  }
  __syncthreads();
  if (t < 196) boff[t] = l[t];
}

// ---------------- scan phase 3 ----------------
__global__ void __launch_bounds__(256) k_scan3(const int* __restrict__ deg,
                        const int* __restrict__ boff, int* __restrict__ rp,
                        int* __restrict__ cursor, float* __restrict__ degf){
  __shared__ int wpre[4];
  int b = blockIdx.x, t = threadIdx.x;
  int i0 = b*512 + 2*t;
  int d0 = (i0     < N_NODES) ? deg[i0]     : 0;
  int d1 = (i0 + 1 < N_NODES) ? deg[i0 + 1] : 0;
  int s = d0 + d1;
  int incl = s;
  for (int o = 1; o < 64; o <<= 1){ int u = __shfl_up(incl, o); if ((t & 63) >= o) incl += u; }
  if ((t & 63) == 63) wpre[t >> 6] = incl;
  __syncthreads();
  if (t == 0){ int r = 0; for (int k = 0; k < 4; k++){ int x = wpre[k]; wpre[k] = r; r += x; } }
  __syncthreads();
  int excl = boff[b] + wpre[t >> 6] + incl - s;
  if (i0 < N_NODES){
    rp[i0] = excl; cursor[i0] = excl; degf[i0] = (float)d0;
  }
  if (i0 + 1 < N_NODES){
    rp[i0+1] = excl + d0; cursor[i0+1] = excl + d0; degf[i0+1] = (float)d1;
  }
}

// ---------------- wave ranges: wr[w] = first node with rp >= w*E/nw -------
__global__ void k_ranges(const int* __restrict__ rp, int* __restrict__ wr,
                         int nwaves){
  int w = blockIdx.x*blockDim.x + threadIdx.x;
  if (w > nwaves) return;
  if (w == nwaves){ wr[w] = N_NODES; return; }
  long long t0 = (long long)w * N_EDGES / nwaves;
  int lo = 0, hi = N_NODES;
  while (lo < hi){ int mid = (lo+hi)>>1; if ((long long)rp[mid] < t0) lo = mid+1; else hi = mid; }
  wr[w] = lo;
}

// ---------------- CSR scatter (fallback path: int2 perm2) ----------------
__global__ void k_scatter(const int* __restrict__ ei, int* __restrict__ cursor,
                          int* __restrict__ perm2){
  int i = blockIdx.x*blockDim.x + threadIdx.x;
  int stride = gridDim.x*blockDim.x;
  for (int e = i; e < N_EDGES; e += stride){
    int d = ei[N_EDGES + e];
    int p = atomicAdd(&cursor[d], 1);
    ((int2*)perm2)[p] = make_int2(ei[e], e);
  }
}

// ---------------- CSR scatter v2: perm (src only) + edge attrs permuted to
// CSR order as bf16.  NT stores: single-use stream, keep out of caches. ----
__global__ void k_scatter2(const int* __restrict__ ei, int* __restrict__ cursor,
                           int* __restrict__ perm, u16* __restrict__ eacsr,
                           const void* __restrict__ ea, const int* __restrict__ flagp){
  int isbf = *flagp;
  int i = blockIdx.x*blockDim.x + threadIdx.x;
  int stride = gridDim.x*blockDim.x;
  if (i < 16){
    perm[N_EDGES + i] = 0;
    uint4 z = make_uint4(0,0,0,0);
    uint4* out = (uint4*)(eacsr + (size_t)(N_EDGES + i)*16);
    ntstore4(out, z); ntstore4(out + 1, z);
  }
  for (int e = i; e < N_EDGES; e += stride){
    int d = ei[N_EDGES + e];
    int p = atomicAdd(&cursor[d], 1);
    perm[p] = ei[e];
    uint4 r0, r1;
    if (isbf){
      const uint4* er = (const uint4*)((const u16*)ea + (size_t)e*16);
      r0 = er[0]; r1 = er[1];
    } else {
      const float4* ef = (const float4*)((const float*)ea + (size_t)e*16);
      float4 f0 = ef[0], f1 = ef[1], f2 = ef[2], f3 = ef[3];
      r0.x = (u32)f2bf(f0.x) | ((u32)f2bf(f0.y)<<16);
      r0.y = (u32)f2bf(f0.z) | ((u32)f2bf(f0.w)<<16);
      r0.z = (u32)f2bf(f1.x) | ((u32)f2bf(f1.y)<<16);
      r0.w = (u32)f2bf(f1.z) | ((u32)f2bf(f1.w)<<16);
      r1.x = (u32)f2bf(f2.x) | ((u32)f2bf(f2.y)<<16);
      r1.y = (u32)f2bf(f2.z) | ((u32)f2bf(f2.w)<<16);
      r1.z = (u32)f2bf(f3.x) | ((u32)f2bf(f3.y)<<16);
      r1.w = (u32)f2bf(f3.z) | ((u32)f2bf(f3.w)<<16);
    }
    uint4* out = (uint4*)(eacsr + (size_t)p*16);
    ntstore4(out, r0); ntstore4(out + 1, r1);
  }
}

// tile-advance: next 16-edge tile after (ni, bi, ei); skips empty nodes.
__device__ __forceinline__ void adv_tile(const int* __restrict__ rp,
                                         int ni, int bi, int ei,
                                         int& no, int& bo, int& eo){
  if (bi + 16 < ei){ no = ni; bo = bi + 16; eo = ei; return; }
  int t = ni + 1;
  int nb = ei;
  int ne = rp[(t < N_NODES) ? t + 1 : N_NODES];
  while (nb == ne && t + 1 < N_NODES){
    t++; nb = ne; ne = rp[t + 1];
  }
  no = t; bo = nb; eo = ne;
}

// ---------------- MFMA message kernel (old, fallback path) ----------------
__global__ void __launch_bounds__(256) k_msgmm(
    const u16* __restrict__ hsp, const void* __restrict__ ea,
    const int* __restrict__ rp, const int* __restrict__ perm2,
    const u16* __restrict__ Wl, u16* __restrict__ aggs,
    float* __restrict__ stats, const int* __restrict__ flagp,
    int nwaves){
  __shared__ float bs[128];
  int tid = threadIdx.x;
  if (tid < 128) bs[tid] = 0.f;
  __syncthreads();
  int isbf = *flagp;
  int lane = tid & 63, wv = tid >> 6;
  int w = blockIdx.x*4 + wv;
  long long t0 = (long long)w     * N_EDGES / nwaves;
  long long t1 = (long long)(w+1) * N_EDGES / nwaves;
  int lo = 0, hi = N_NODES;
  while (lo < hi){ int mid = (lo+hi)>>1; if ((long long)rp[mid] < t0) lo = mid+1; else hi = mid; }
  int n0 = lo, n1;
  if (w == nwaves-1) n1 = N_NODES;
  else {
    lo = 0; hi = N_NODES;
    while (lo < hi){ int mid = (lo+hi)>>1; if ((long long)rp[mid] < t1) lo = mid+1; else hi = mid; }
    n1 = lo;
  }
  int nn = lane & 15, kg = lane >> 4;
  bf16x8 B[3][4];
#pragma unroll
  for (int t = 0; t < 4; t++)
#pragma unroll
    for (int kb = 0; kb < 3; kb++)
      B[kb][t] = *(const bf16x8*)(Wl + (size_t)(t*16+nn)*96 + kb*32 + kg*8);
  U4BF ac; ac.u = make_uint4((kg==2)? 0x3f80u : 0u, 0u, 0u, 0u);
  float s1[4] = {0,0,0,0}, s2[4] = {0,0,0,0};
  for (int n = n0; n < n1; n++){
    int b0 = rp[n], b1 = rp[n+1];
    float r0 = 0.f, r1 = 0.f, r2 = 0.f, r3 = 0.f;
    for (int base = b0; base < b1; base += 16){
      int rem = b1 - base; if (rem > 16) rem = 16;
      int row = (nn < rem) ? nn : rem-1;
      int2 p = ((const int2*)perm2)[base + row];
      const uint4* hp = (const uint4*)(hsp + (size_t)p.x*128);
      U4BF fA, fB, fC;
      fA.u = hp[kg];
      fB.u = hp[4 + kg];
      if (kg < 2){
        if (isbf){
          fC.u = ((const uint4*)ea)[(size_t)p.y*2 + kg];
        } else {
          const float4* ef = (const float4*)ea;
          float4 f0 = ef[(size_t)p.y*4 + kg*2];
          float4 f1 = ef[(size_t)p.y*4 + kg*2 + 1];
          fC.u.x = (u32)f2bf(f0.x) | ((u32)f2bf(f0.y)<<16);
          fC.u.y = (u32)f2bf(f0.z) | ((u32)f2bf(f0.w)<<16);
          fC.u.z = (u32)f2bf(f1.x) | ((u32)f2bf(f1.y)<<16);
          fC.u.w = (u32)f2bf(f1.z) | ((u32)f2bf(f1.w)<<16);
        }
      } else fC = ac;
      f32x4 a0 = {0,0,0,0}, a1 = {0,0,0,0}, a2 = {0,0,0,0}, a3 = {0,0,0,0};
      a0 = __builtin_amdgcn_mfma_f32_16x16x32_bf16(fA.v, B[0][0], a0, 0,0,0);
      a1 = __builtin_amdgcn_mfma_f32_16x16x32_bf16(fA.v, B[0][1], a1, 0,0,0);
      a2 = __builtin_amdgcn_mfma_f32_16x16x32_bf16(fA.v, B[0][2], a2, 0,0,0);
      a3 = __builtin_amdgcn_mfma_f32_16x16x32_bf16(fA.v, B[0][3], a3, 0,0,0);
      a0 = __builtin_amdgcn_mfma_f32_16x16x32_bf16(fB.v, B[1][0], a0, 0,0,0);
      a1 = __builtin_amdgcn_mfma_f32_16x16x32_bf16(fB.v, B[1][1], a1, 0,0,0);
      a2 = __builtin_amdgcn_mfma_f32_16x16x32_bf16(fB.v, B[1][2], a2, 0,0,0);
      a3 = __builtin_amdgcn_mfma_f32_16x16x32_bf16(fB.v, B[1][3], a3, 0,0,0);
      a0 = __builtin_amdgcn_mfma_f32_16x16x32_bf16(fC.v, B[2][0], a0, 0,0,0);
      a1 = __builtin_amdgcn_mfma_f32_16x16x32_bf16(fC.v, B[2][1], a1, 0,0,0);
      a2 = __builtin_amdgcn_mfma_f32_16x16x32_bf16(fC.v, B[2][2], a2, 0,0,0);
      a3 = __builtin_amdgcn_mfma_f32_16x16x32_bf16(fC.v, B[2][3], a3, 0,0,0);
      int rowbase = kg*4;
      float ts0 = 0.f, ts1 = 0.f, ts2 = 0.f, ts3 = 0.f;
#pragma unroll
      for (int j = 0; j < 4; j++){
        bool valid = (rowbase + j) < rem;
        float m0 = fmaxf(a0[j], 0.f); m0 = valid ? m0 : 0.f;
        float m1 = fmaxf(a1[j], 0.f); m1 = valid ? m1 : 0.f;
        float m2 = fmaxf(a2[j], 0.f); m2 = valid ? m2 : 0.f;
        float m3 = fmaxf(a3[j], 0.f); m3 = valid ? m3 : 0.f;
        ts0 += m0; ts1 += m1; ts2 += m2; ts3 += m3;
        s2[0] = fmaf(m0,m0,s2[0]); s2[1] = fmaf(m1,m1,s2[1]);
        s2[2] = fmaf(m2,m2,s2[2]); s2[3] = fmaf(m3,m3,s2[3]);
      }
      s1[0] += ts0; s1[1] += ts1; s1[2] += ts2; s1[3] += ts3;
      ts0 += __shfl_xor(ts0,16); ts0 += __shfl_xor(ts0,32);
      ts1 += __shfl_xor(ts1,16); ts1 += __shfl_xor(ts1,32);
      ts2 += __shfl_xor(ts2,16); ts2 += __shfl_xor(ts2,32);
      ts3 += __shfl_xor(ts3,16); ts3 += __shfl_xor(ts3,32);
      r0 += ts0; r1 += ts1; r2 += ts2; r3 += ts3;
    }
    float v = (kg==0) ? r0 : (kg==1) ? r1 : (kg==2) ? r2 : r3;
    u16 hiv = f2bf(v);
    aggs[(size_t)n*128 + lane]      = hiv;
    aggs[(size_t)n*128 + 64 + lane] = f2bf(v - bf2f(hiv));
  }
#pragma unroll
  for (int t = 0; t < 4; t++){
    atomicAdd(&bs[t*16+nn], s1[t]);
    atomicAdd(&bs[64+t*16+nn], s2[t]);
  }
  __syncthreads();
  if (tid < 128) atomicAdd(&stats[tid], bs[tid]);
}

// ---------------- MFMA message kernel v2: 2-stage pipeline (r3-proven) +
// NT loads on single-use streams (perm, eacsr) so the h gather set stays
// cache-resident; wave ranges precomputed (no per-wave binary search).
__global__ void __launch_bounds__(256) k_msgmm2(
    const u16* __restrict__ hsp, const u16* __restrict__ eacsr,
    const int* __restrict__ rp, const int* __restrict__ perm,
    const u16* __restrict__ Wl, u16* __restrict__ aggs,
    float* __restrict__ stats, const int* __restrict__ wranges){
  __shared__ float bs[128];
  int tid = threadIdx.x;
  if (tid < 128) bs[tid] = 0.f;
  __syncthreads();
  int lane = tid & 63;
  int w = blockIdx.x*4 + (tid >> 6);
  int nBeg = wranges[w], nEnd = wranges[w+1];
  int nn = lane & 15, kg = lane >> 4;
  bf16x8 B[3][4];
#pragma unroll
  for (int t = 0; t < 4; t++)
#pragma unroll
    for (int kb = 0; kb < 3; kb++)
      B[kb][t] = *(const bf16x8*)(Wl + (size_t)(t*16+nn)*96 + kb*32 + kg*8);
  U4BF ac; ac.u = make_uint4((kg==2)? 0x3f80u : 0u, 0u, 0u, 0u);
  float s1[4] = {0,0,0,0}, s2[4] = {0,0,0,0};

  if (nBeg < nEnd){
    // pre-pass: zero rows of empty nodes (rare; main walk skips them)
    {
      int pv = rp[nBeg];
      for (int m = nBeg; m < nEnd; m++){
        int nx = rp[m+1];
        if (nx == pv){
          aggs[(size_t)m*128 + lane] = 0;
          aggs[(size_t)m*128 + 64 + lane] = 0;
        }
        pv = nx;
      }
    }
    // initial tile: first non-empty node
    int nA = nBeg;
    int baseA = rp[nA], b1A = rp[nA+1];
    while (baseA == b1A && nA + 1 < nEnd){ nA++; baseA = b1A; b1A = rp[nA+1]; }
    if (baseA < b1A){
      int nB, baseB, b1B;
      adv_tile(rp, nA, baseA, b1A, nB, baseB, b1B);
      int pB = __builtin_nontemporal_load(&perm[baseB + nn]);
      // prologue loads for tile A
      U4BF fAA, fAB, fAC;
      {
        int pA = __builtin_nontemporal_load(&perm[baseA + nn]);
        const uint4* hpA = (const uint4*)(hsp + (size_t)pA*128);
        fAA.u = hpA[kg]; fAB.u = hpA[4 + kg];
        if (kg < 2) fAC.u = ntload4(eacsr + ((size_t)baseA + nn)*16 + (size_t)kg*8);
        else fAC = ac;
      }
      float r0 = 0.f, r1 = 0.f, r2 = 0.f, r3 = 0.f;
      while (true){
        // coords for t+2, prefetch its perm
        int nC, baseC, b1C;
        adv_tile(rp, nB, baseB, b1B, nC, baseC, b1C);
        int pC = __builtin_nontemporal_load(&perm[baseC + nn]);
        // prefetch tile B operands (overlap with MFMA of tile A)
        const uint4* hpB = (const uint4*)(hsp + (size_t)pB*128);
        U4BF fBA, fBB, fBC;
        fBA.u = hpB[kg]; fBB.u = hpB[4 + kg];
        if (kg < 2) fBC.u = ntload4(eacsr + ((size_t)baseB + nn)*16 + (size_t)kg*8);
        else fBC = ac;
        // MFMA on tile A
        f32x4 a0 = {0,0,0,0}, a1 = {0,0,0,0}, a2 = {0,0,0,0}, a3 = {0,0,0,0};
        a0 = __builtin_amdgcn_mfma_f32_16x16x32_bf16(fAA.v, B[0][0], a0, 0,0,0);
        a1 = __builtin_amdgcn_mfma_f32_16x16x32_bf16(fAA.v, B[0][1], a1, 0,0,0);
        a2 = __builtin_amdgcn_mfma_f32_16x16x32_bf16(fAA.v, B[0][2], a2, 0,0,0);
        a3 = __builtin_amdgcn_mfma_f32_16x16x32_bf16(fAA.v, B[0][3], a3, 0,0,0);
        a0 = __builtin_amdgcn_mfma_f32_16x16x32_bf16(fAB.v, B[1][0], a0, 0,0,0);
        a1 = __builtin_amdgcn_mfma_f32_16x16x32_bf16(fAB.v, B[1][1], a1, 0,0,0);
        a2 = __builtin_amdgcn_mfma_f32_16x16x32_bf16(fAB.v, B[1][2], a2, 0,0,0);
        a3 = __builtin_amdgcn_mfma_f32_16x16x32_bf16(fAB.v, B[1][3], a3, 0,0,0);
        a0 = __builtin_amdgcn_mfma_f32_16x16x32_bf16(fAC.v, B[2][0], a0, 0,0,0);
        a1 = __builtin_amdgcn_mfma_f32_16x16x32_bf16(fAC.v, B[2][1], a1, 0,0,0);
        a2 = __builtin_amdgcn_mfma_f32_16x16x32_bf16(fAC.v, B[2][2], a2, 0,0,0);
        a3 = __builtin_amdgcn_mfma_f32_16x16x32_bf16(fAC.v, B[2][3], a3, 0,0,0);
        // epilogue for tile A
        int rem = b1A - baseA; if (rem > 16) rem = 16;
        int rowbase = kg*4;
        float ts0 = 0.f, ts1 = 0.f, ts2 = 0.f, ts3 = 0.f;
#pragma unroll
        for (int j = 0; j < 4; j++){
          bool valid = (rowbase + j) < rem;
          float m0 = fmaxf(a0[j], 0.f); m0 = valid ? m0 : 0.f;
          float m1 = fmaxf(a1[j], 0.f); m1 = valid ? m1 : 0.f;
          float m2 = fmaxf(a2[j], 0.f); m2 = valid ? m2 : 0.f;
          float m3 = fmaxf(a3[j], 0.f); m3 = valid ? m3 : 0.f;
          ts0 += m0; ts1 += m1; ts2 += m2; ts3 += m3;
          s2[0] = fmaf(m0,m0,s2[0]); s2[1] = fmaf(m1,m1,s2[1]);
          s2[2] = fmaf(m2,m2,s2[2]); s2[3] = fmaf(m3,m3,s2[3]);
        }
        s1[0] += ts0; s1[1] += ts1; s1[2] += ts2; s1[3] += ts3;
        r0 += ts0; r1 += ts1; r2 += ts2; r3 += ts3;
        if (baseA + 16 >= b1A){          // last tile of node nA
          r0 += __shfl_xor(r0,16); r0 += __shfl_xor(r0,32);
          r1 += __shfl_xor(r1,16); r1 += __shfl_xor(r1,32);
          r2 += __shfl_xor(r2,16); r2 += __shfl_xor(r2,32);
          r3 += __shfl_xor(r3,16); r3 += __shfl_xor(r3,32);
          float v = (kg==0) ? r0 : (kg==1) ? r1 : (kg==2) ? r2 : r3;
          u16 hiv = f2bf(v);
          aggs[(size_t)nA*128 + lane]      = hiv;
          aggs[(size_t)nA*128 + 64 + lane] = f2bf(v - bf2f(hiv));
          r0 = r1 = r2 = r3 = 0.f;
        }
        // rotate pipeline
        nA = nB; baseA = baseB; b1A = b1B;
        fAA = fBA; fAB = fBB; fAC = fBC;
        nB = nC; baseB = baseC; b1B = b1C; pB = pC;
        if (nA >= nEnd) break;
      }
    }
  }
#pragma unroll
  for (int t = 0; t < 4; t++){
    atomicAdd(&bs[t*16+nn], s1[t]);
    atomicAdd(&bs[64+t*16+nn], s2[t]);
  }
  __syncthreads();
  if (tid < 128) atomicAdd(&stats[tid], bs[tid]);
}

// ---------------- BN finalize (self-zeroes stats) ----------------
__global__ void k_fin(float* __restrict__ stats, const void* __restrict__ gamma,
                      const void* __restrict__ beta, float* __restrict__ aff,
                      float cnt_inv, int goff, const int* __restrict__ flagp){
  int isbf = *flagp; int c = threadIdx.x;
  float mu  = stats[c]      * cnt_inv;
  float var = stats[64 + c] * cnt_inv - mu*mu;
  float rs  = rsqrtf(var + 1e-5f);
  float g = ldf(gamma, (size_t)goff + c, isbf);
  float b = ldf(beta,  (size_t)goff + c, isbf);
  aff[c]      = g*rs;
  aff[64 + c] = b - g*mu*rs;
  stats[c] = 0.f; stats[64 + c] = 0.f;
}

// ---------------- MFMA fused update, split-precision ----------------
// h input is PRE-BN (haff folded into Wa via updprep); agg in G; writes
// pre-BN relu(u) split hi/lo IN PLACE over G (wave owns its 16 rows).
// Both inputs are LAST-USE streams here -> NT loads (protect gather set).
#define UPD_TILES (N_NODES/16)
__global__ void __launch_bounds__(256) k_updmm(
    const u16* __restrict__ hsp, u16* __restrict__ aggs,
    const float* __restrict__ degf, const u16* __restrict__ Wupd,
    const float* __restrict__ biasv, const float* __restrict__ tvv,
    float* __restrict__ stats){
  __shared__ float bs[128];
  int tid = threadIdx.x;
  if (tid < 128) bs[tid] = 0.f;
  __syncthreads();
  int lane = tid & 63;
  int nn = lane & 15, kg = lane >> 4;
  int w = blockIdx.x*4 + (tid >> 6);
  int nwv = gridDim.x*4;
  bf16x8 B[6][4];
#pragma unroll
  for (int t = 0; t < 4; t++)
#pragma unroll
    for (int kb = 0; kb < 6; kb++)
      B[kb][t] = *(const bf16x8*)(Wupd + (size_t)(t*16+nn)*192 + kb*32 + kg*8);
  float bc[4], tc[4];
#pragma unroll
  for (int t = 0; t < 4; t++){ bc[t] = biasv[t*16+nn]; tc[t] = tvv[t*16+nn]; }
  float s1[4] = {0,0,0,0}, s2[4] = {0,0,0,0};
  for (int tile = w; tile < UPD_TILES; tile += nwv){
    int n0 = tile*16;
    int r = n0 + nn;
    const uint4* hp = (const uint4*)hsp;
    const uint4* ap = (const uint4*)aggs;
    U4BF hh0, hh1, hl0, hl1, ah0, ah1, al0, al1;
    hh0.u = ntload4(&hp[(size_t)r*16 + kg]);       hh1.u = ntload4(&hp[(size_t)r*16 + 4 + kg]);
    hl0.u = ntload4(&hp[(size_t)r*16 + 8 + kg]);   hl1.u = ntload4(&hp[(size_t)r*16 + 12 + kg]);
    ah0.u = ntload4(&ap[(size_t)r*16 + kg]);       ah1.u = ntload4(&ap[(size_t)r*16 + 4 + kg]);
    al0.u = ntload4(&ap[(size_t)r*16 + 8 + kg]);   al1.u = ntload4(&ap[(size_t)r*16 + 12 + kg]);
    float dg[4];
#pragma unroll
    for (int j = 0; j < 4; j++) dg[j] = degf[n0 + kg*4 + j];
    f32x4 a0 = {0,0,0,0}, a1 = {0,0,0,0}, a2 = {0,0,0,0}, a3 = {0,0,0,0};
#define MF(F,KB) \
    a0 = __builtin_amdgcn_mfma_f32_16x16x32_bf16(F.v, B[KB][0], a0, 0,0,0); \
    a1 = __builtin_amdgcn_mfma_f32_16x16x32_bf16(F.v, B[KB][1], a1, 0,0,0); \
    a2 = __builtin_amdgcn_mfma_f32_16x16x32_bf16(F.v, B[KB][2], a2, 0,0,0); \
    a3 = __builtin_amdgcn_mfma_f32_16x16x32_bf16(F.v, B[KB][3], a3, 0,0,0);
    MF(hh0,0) MF(hh1,1) MF(hl0,0) MF(hl1,1)
    MF(ah0,2) MF(ah1,3) MF(ah0,4) MF(ah1,5)
    MF(al0,2) MF(al1,3)
#undef MF
#pragma unroll
    for (int j = 0; j < 4; j++){
      int n = n0 + kg*4 + j;
      float m0 = fmaxf(fmaf(tc[0], dg[j], a0[j] + bc[0]), 0.f);
      float m1 = fmaxf(fmaf(tc[1], dg[j], a1[j] + bc[1]), 0.f);
      float m2 = fmaxf(fmaf(tc[2], dg[j], a2[j] + bc[2]), 0.f);
      float m3 = fmaxf(fmaf(tc[3], dg[j], a3[j] + bc[3]), 0.f);
      s1[0] += m0; s1[1] += m1; s1[2] += m2; s1[3] += m3;
      s2[0] = fmaf(m0,m0,s2[0]); s2[1] = fmaf(m1,m1,s2[1]);
      s2[2] = fmaf(m2,m2,s2[2]); s2[3] = fmaf(m3,m3,s2[3]);
      u16* hw = aggs + (size_t)n*128;
      u16 q0 = f2bf(m0), q1 = f2bf(m1), q2 = f2bf(m2), q3 = f2bf(m3);
      hw[     nn] = q0;  hw[64 +      nn] = f2bf(m0 - bf2f(q0));
      hw[16 + nn] = q1;  hw[64 + 16 + nn] = f2bf(m1 - bf2f(q1));
      hw[32 + nn] = q2;  hw[64 + 32 + nn] = f2bf(m2 - bf2f(q2));
      hw[48 + nn] = q3;  hw[64 + 48 + nn] = f2bf(m3 - bf2f(q3));
    }
  }
#pragma unroll
  for (int t = 0; t < 4; t++){
    atomicAdd(&bs[t*16+nn], s1[t]);
    atomicAdd(&bs[64+t*16+nn], s2[t]);
  }
  __syncthreads();
  if (tid < 128) atomicAdd(&stats[tid], bs[tid]);
}

// ---------------- global add pool over PRE-BN h with affine applied:
// g[b] = s * sum(u) + t * count(b) ----------------
__global__ void k_pool(const u16* __restrict__ hsp, const int* __restrict__ batch,
                       const float* __restrict__ aff, float* __restrict__ g){
  int lane = threadIdx.x & 63;
  int gw = (blockIdx.x*blockDim.x + threadIdx.x) >> 6;
  int nw = (gridDim.x*blockDim.x) >> 6;
  float s = aff[lane], t = aff[64 + lane];
  int chunk = (N_NODES + nw - 1) / nw;
  int n0 = gw*chunk;
  int n1 = n0 + chunk; if (n1 > N_NODES) n1 = N_NODES;
  int cur = -1; float acc = 0.f, cnt = 0.f;
  for (int n = n0; n < n1; n++){
    int b = batch[n];
    float v = bf2f(hsp[(size_t)n*128 + lane]) + bf2f(hsp[(size_t)n*128 + 64 + lane]);
    if (b != cur){
      if (cur >= 0) atomicAdd(&g[(size_t)cur*64 + lane], fmaf(s, acc, t*cnt));
      cur = b; acc = v; cnt = 1.f;
    } else { acc += v; cnt += 1.f; }
  }
  if (cur >= 0) atomicAdd(&g[(size_t)cur*64 + lane], fmaf(s, acc, t*cnt));
}

// ---------------- readout ----------------
__global__ void k_read(const float* __restrict__ g, const void* __restrict__ r1W,
                       const void* __restrict__ r1b, const void* __restrict__ r2W,
                       const void* __restrict__ r2b, void* __restrict__ out,
                       const int* __restrict__ flagp){
  int isbf = *flagp;
  int lane = threadIdx.x;
  int gr = blockIdx.x;
  float w[64];
#pragma unroll
  for (int k = 0; k < 64; k++) w[k] = ldf(r1W, (size_t)k*64 + lane, isbf);
  float acc = ldf(r1b, lane, isbf);
  const float4* grow = (const float4*)(g + (size_t)gr*64);
#pragma unroll
  for (int q = 0; q < 16; q++){
    float4 a = grow[q];
    acc = fmaf(a.x, w[4*q+0], acc); acc = fmaf(a.y, w[4*q+1], acc);
    acc = fmaf(a.z, w[4*q+2], acc); acc = fmaf(a.w, w[4*q+3], acc);
  }
  float hid = fmaxf(acc, 0.f);
  float p = hid * ldf(r2W, lane, isbf);
  for (int o = 32; o; o >>= 1) p += __shfl_xor(p, o);
  if (lane == 0){
    float v = p + ldf(r2b, 0, isbf);
    if (isbf) ((__hip_bfloat16*)out)[gr] = __float2bfloat16(v);
    else      ((float*)out)[gr] = v;
  }
}

extern "C" void kernel_launch(void* const* d_in, const int* in_sizes, int n_in,
                              void* d_out, int out_size, void* d_ws, size_t ws_size,
                              hipStream_t stream){
  const void* x    = d_in[0];
  const void* ea   = d_in[1];
  const int*  ei   = (const int*)d_in[2];
  const int*  bt   = (const int*)d_in[3];
  const void* nW   = d_in[4];  const void* nb  = d_in[5];
  const void* eW   = d_in[6];  const void* eb  = d_in[7];
  const void* mW   = d_in[8];  const void* mb  = d_in[9];
  const void* mg   = d_in[10]; const void* mbe = d_in[11];
  const void* uW   = d_in[12]; const void* ub  = d_in[13];
  const void* ug   = d_in[14]; const void* ube = d_in[15];
  const void* r1W  = d_in[16]; const void* r1b = d_in[17];
  const void* r2W  = d_in[18]; const void* r2b = d_in[19];

  // big path needs 27,692,011 floats = 110,768,044 bytes
  const size_t NEED_BIG = 110768044ull;
  const bool big = (ws_size >= NEED_BIG);

  float* ws = (float*)d_ws;
  size_t off = 0;
  auto alloc = [&](size_t n){ float* p = ws + off; off += n; return p; };

  u16*   hsp   = (u16*)alloc(6400000);
  u16*   aggs  = (u16*)alloc(6400000);
  u16*   eacsr = nullptr; int* perm = nullptr; int* perm2 = nullptr;
  if (big){
    eacsr = (u16*)alloc(12800128);          // (E+16) rows x 16 u16
    perm  = (int*)alloc(1600016);           // E+16 ints
  } else {
    perm2 = (int*)alloc(3200000);           // E int2
  }
  float* degf   = alloc(100000);
  float* zero0  = ws + off;                 // memset region start
  int*   deg_i  = (int*)alloc(100000);
  float* g      = alloc(64000);
  float* mstats = alloc(128);
  float* ustats = alloc(128);
  size_t zeroN  = (size_t)((ws + off) - zero0);   // 164,256 floats
  float* maff   = alloc(128);
  float* haff   = alloc(128);
  int*   flag   = (int*)alloc(16);
  u16*   Weff   = (u16*)alloc(9216);        // base msg weights (3 layers)
  u16*   Wfold  = (u16*)alloc(3072);        // per-layer folded msg weights
  u16*   Wupd   = (u16*)alloc(6144);
  float* biasm  = alloc(192);               // f32 base msg bias (3 layers)
  float* biasv  = alloc(64);
  float* tvv    = alloc(64);
  int*   row_ptr= (int*)alloc(100001);
  int*   cursor = (int*)alloc(100000);
  int*   bsum   = (int*)alloc(196);
  int*   boff   = (int*)alloc(196);
  int*   wrng   = (int*)alloc(8194);        // wave ranges (MM_WAVES+1)

  const int MM_BLOCKS = 2048;
  const int MM_WAVES  = MM_BLOCKS * 4;
  const int UPD_BLOCKS = 782;

  k_detect<<<1, 64, 0, stream>>>((const u32*)x, flag);
  hipMemsetAsync(zero0, 0, zeroN*sizeof(float), stream);
  k_idaff<<<1, 64, 0, stream>>>(haff);
  k_prep<<<3, 64, 0, stream>>>(eW, eb, mW, mb, Weff, biasm, flag);
  k_node_emb<<<256, 256, 0, stream>>>(x, nW, nb, hsp, flag);
  k_deg<<<512, 256, 0, stream>>>(ei, deg_i);
  k_scan1<<<196, 256, 0, stream>>>(deg_i, bsum);
  k_scan2<<<1, 256, 0, stream>>>(bsum, boff, row_ptr);
  k_scan3<<<196, 256, 0, stream>>>(deg_i, boff, row_ptr, cursor, degf);
  if (big){
    k_ranges<<<33, 256, 0, stream>>>(row_ptr, wrng, MM_WAVES);
    k_scatter2<<<512, 256, 0, stream>>>(ei, cursor, perm, eacsr, ea, flag);
  } else {
    k_scatter<<<512, 256, 0, stream>>>(ei, cursor, perm2);
  }

  u16* H = hsp;   // current h (layer 0: embedding; l>0: pre-BN relu(u), haff pending)
  u16* G = aggs;  // scratch: msg agg, then overwritten by pre-BN relu(u)
  for (int l = 0; l < 3; l++){
    k_fold<<<1, 64, 0, stream>>>(mW, Weff, biasm, haff, Wfold, flag, l);
    if (big)
      k_msgmm2<<<MM_BLOCKS, 256, 0, stream>>>(H, eacsr, row_ptr, perm, Wfold,
                                              G, mstats, wrng);
    else
      k_msgmm<<<MM_BLOCKS, 256, 0, stream>>>(H, ea, row_ptr, perm2, Wfold,
                                             G, mstats, flag, MM_WAVES);
    k_fin<<<1, 64, 0, stream>>>(mstats, mg, mbe, maff, 1.0f/(float)N_EDGES, l*64, flag);
    k_updprep<<<1, 64, 0, stream>>>(uW, ub, maff, haff, Wupd, biasv, tvv, flag, l);
    k_updmm<<<UPD_BLOCKS, 256, 0, stream>>>(H, G, degf, Wupd, biasv, tvv, ustats);
    k_fin<<<1, 64, 0, stream>>>(ustats, ug, ube, haff, 1.0f/(float)N_NODES, l*64, flag);
    u16* tmp = H; H = G; G = tmp;
  }

  k_pool<<<128, 256, 0, stream>>>(H, bt, haff, g);
  k_read<<<NUM_GRAPHS, 64, 0, stream>>>(g, r1W, r1b, r2W, r2b, d_out, flag);
}

// Round 12
// 1367.988 us; speedup vs baseline: 1.0329x; 1.0329x over previous
//
#include <hip/hip_runtime.h>
#include <hip/hip_bf16.h>

#define N_NODES   100000
#define N_EDGES   1600000
#define NUM_GRAPHS 1000

typedef unsigned int u32;
typedef unsigned short u16;

typedef __bf16 bf16_t;
typedef bf16_t bf16x8 __attribute__((ext_vector_type(8)));
typedef float  f32x4  __attribute__((ext_vector_type(4)));
typedef u32    u32x4  __attribute__((ext_vector_type(4)));

__device__ __forceinline__ float bf2f(u16 u){ return __uint_as_float(((u32)u)<<16); }
__device__ __forceinline__ float BL(u32 u){ return __uint_as_float(u<<16); }
__device__ __forceinline__ float BH(u32 u){ return __uint_as_float(u&0xffff0000u); }
// f32 -> bf16 bits, round-to-nearest-even
__device__ __forceinline__ u16 f2bf(float f){
  u32 u = __float_as_uint(f);
  return (u16)((u + 0x7fffu + ((u>>16)&1u)) >> 16);
}
// dual-dtype scalar load: isbf=1 -> bf16, else f32
__device__ __forceinline__ float ldf(const void* p, size_t i, int isbf){
  return isbf ? bf2f(((const u16*)p)[i]) : ((const float*)p)[i];
}
// non-temporal 16B load (streaming reads, keep out of L2/L3 hot set).
// NOTE (r8 post-mortem): NT *stores* on random scatters regressed 3x
// (write amplification, no L2 coalescing) — loads only.
__device__ __forceinline__ uint4 ntload4(const void* p){
  u32x4 v = __builtin_nontemporal_load((const u32x4*)p);
  return make_uint4(v.x, v.y, v.z, v.w);
}

union U4BF { uint4 u; bf16x8 v; };

// ---------------- dtype detector ----------------
__global__ void k_detect(const u32* __restrict__ x, int* __restrict__ flag){
  int t = threadIdx.x; int cnt = 0;
  for (int i = t; i < 256; i += 64){
    u32 w = x[i];
    u32 e = (w >> 7) & 0xffu;
    if (e >= 110u && e <= 137u) cnt++;
  }
  for (int o = 32; o; o >>= 1) cnt += __shfl_xor(cnt, o);
  if (t == 0) *flag = (cnt > 128) ? 1 : 0;
}

// ---------------- identity affine init: s=1, t=0 ----------------
__global__ void k_idaff(float* __restrict__ haff){
  int c = threadIdx.x;
  haff[c] = 1.f; haff[64 + c] = 0.f;
}

// ---------------- weight prep: base Weff[l][c][96] + f32 base bias ---------
__global__ void k_prep(const void* __restrict__ eW, const void* __restrict__ eb,
                       const void* __restrict__ mW, const void* __restrict__ mb,
                       u16* __restrict__ Weff, float* __restrict__ biasm,
                       const int* __restrict__ flagp){
  int isbf = *flagp;
  int l = blockIdx.x, c = threadIdx.x;
  u16* W = Weff + ((size_t)l*64 + c)*96;
  for (int k = 0; k < 64; k++)
    W[k] = f2bf(ldf(mW, (size_t)(l*96 + k)*64 + c, isbf));
  for (int j = 0; j < 16; j++){
    float acc = 0.f;
    for (int k = 0; k < 32; k++)
      acc += ldf(eW, (size_t)j*32 + k, isbf) * ldf(mW, (size_t)(l*96 + 64 + k)*64 + c, isbf);
    W[64 + j] = f2bf(acc);
  }
  float fbv = ldf(mb, (size_t)l*64 + c, isbf);
  for (int k = 0; k < 32; k++)
    fbv += ldf(eb, k, isbf) * ldf(mW, (size_t)(l*96 + 64 + k)*64 + c, isbf);
  W[80] = f2bf(fbv);
  biasm[(size_t)l*64 + c] = fbv;
  for (int k = 81; k < 96; k++) W[k] = 0;
}

// ---------------- per-layer msg-weight fold ----------------
__global__ void k_fold(const void* __restrict__ mW, const u16* __restrict__ Wbase,
                       const float* __restrict__ biasm, const float* __restrict__ haff,
                       u16* __restrict__ Wf, const int* __restrict__ flagp, int l){
  int isbf = *flagp; int c = threadIdx.x;
  const u16* Wb = Wbase + ((size_t)l*64 + c)*96;
  u16* W = Wf + (size_t)c*96;
  float bb = biasm[(size_t)l*64 + c];
  for (int k = 0; k < 64; k++){
    float w = ldf(mW, (size_t)(l*96 + k)*64 + c, isbf);
    W[k] = f2bf(haff[k] * w);
    bb = fmaf(haff[64 + k], w, bb);
  }
  for (int k = 64; k < 80; k++) W[k] = Wb[k];
  W[80] = f2bf(bb);
  for (int k = 81; k < 96; k++) W[k] = 0;
}

// ---------------- update-weight prep ----------------
__global__ void k_updprep(const void* __restrict__ uW, const void* __restrict__ ub,
                          const float* __restrict__ maff, const float* __restrict__ haff,
                          u16* __restrict__ Wupd, float* __restrict__ biasv,
                          float* __restrict__ tvv, const int* __restrict__ flagp, int l){
  int isbf = *flagp; int c = threadIdx.x;
  u16* W = Wupd + (size_t)c*192;
  float tv = 0.f, bb = 0.f;
  for (int k = 0; k < 64; k++){
    float wka = ldf(uW, (size_t)(l*128 + k)*64 + c, isbf);
    W[k] = f2bf(haff[k] * wka);
    bb = fmaf(haff[64 + k], wka, bb);
    float wkb = ldf(uW, (size_t)(l*128 + 64 + k)*64 + c, isbf);
    float prod = wkb * maff[k];
    u16 hi = f2bf(prod);
    W[64 + k]  = hi;
    W[128 + k] = f2bf(prod - bf2f(hi));
    tv = fmaf(maff[64 + k], wkb, tv);
  }
  biasv[c] = ldf(ub, (size_t)l*64 + c, isbf) + bb;
  tvv[c] = tv;
}

// ---------------- node embedding -> hsp split hi/lo ----
__global__ void k_node_emb(const void* __restrict__ x, const void* __restrict__ nW,
                           const void* __restrict__ nb, u16* __restrict__ hsp,
                           const int* __restrict__ flagp){
  int isbf = *flagp;
  int lane = threadIdx.x & 63;
  int gw = (blockIdx.x*blockDim.x + threadIdx.x) >> 6;
  int nw = (gridDim.x*blockDim.x) >> 6;
  float w[32];
#pragma unroll
  for (int k = 0; k < 32; k++) w[k] = ldf(nW, (size_t)k*64 + lane, isbf);
  float bias = ldf(nb, lane, isbf);
  for (int n = gw; n < N_NODES; n += nw){
    float acc = bias;
    if (isbf){
      const uint4* xr = (const uint4*)((const u16*)x + (size_t)n*32);
#pragma unroll
      for (int q = 0; q < 4; q++){
        uint4 a = xr[q];
        u32 uu[4] = {a.x, a.y, a.z, a.w};
#pragma unroll
        for (int j = 0; j < 4; j++){
          acc = fmaf(BL(uu[j]), w[q*8 + 2*j + 0], acc);
          acc = fmaf(BH(uu[j]), w[q*8 + 2*j + 1], acc);
        }
      }
    } else {
      const float4* xr = (const float4*)((const float*)x + (size_t)n*32);
#pragma unroll
      for (int q = 0; q < 8; q++){
        float4 a = xr[q];
        acc = fmaf(a.x, w[q*4+0], acc); acc = fmaf(a.y, w[q*4+1], acc);
        acc = fmaf(a.z, w[q*4+2], acc); acc = fmaf(a.w, w[q*4+3], acc);
      }
    }
    u16 hi = f2bf(acc);
    hsp[(size_t)n*128 + lane]      = hi;
    hsp[(size_t)n*128 + 64 + lane] = f2bf(acc - bf2f(hi));
  }
}

// ---------------- in-degree histogram ----------------
__global__ void k_deg(const int* __restrict__ ei, int* __restrict__ deg){
  int i = blockIdx.x*blockDim.x + threadIdx.x;
  int stride = gridDim.x*blockDim.x;
  for (int e = i; e < N_EDGES; e += stride)
    atomicAdd(&deg[ei[N_EDGES + e]], 1);
}

// ---------------- multi-block scan: phase 1 ----------------
__global__ void __launch_bounds__(256) k_scan1(const int* __restrict__ deg,
                                               int* __restrict__ bsum){
  __shared__ int wsum[4];
  int b = blockIdx.x, t = threadIdx.x;
  int i0 = b*512 + t;
  int s = 0;
  if (i0 < N_NODES) s += deg[i0];
  if (i0 + 256 < N_NODES) s += deg[i0 + 256];
  for (int o = 32; o; o >>= 1) s += __shfl_xor(s, o);
  if ((t & 63) == 0) wsum[t >> 6] = s;
  __syncthreads();
  if (t == 0) bsum[b] = wsum[0] + wsum[1] + wsum[2] + wsum[3];
}

// ---------------- scan phase 2 ----------------
__global__ void k_scan2(const int* __restrict__ bsum, int* __restrict__ boff,
                        int* __restrict__ rp){
  __shared__ int l[200];
  int t = threadIdx.x;
  if (t < 196) l[t] = bsum[t];
  __syncthreads();
  if (t == 0){
    int r = 0;
    for (int k = 0; k < 196; k++){ int x = l[k]; l[k] = r; r += x; }
    rp[N_NODES] = r;
  }
  __syncthreads();
  if (t < 196) boff[t] = l[t];
}

// ---------------- scan phase 3 ----------------
__global__ void __launch_bounds__(256) k_scan3(const int* __restrict__ deg,
                        const int* __restrict__ boff, int* __restrict__ rp,
                        int* __restrict__ cursor, float* __restrict__ degf){
  __shared__ int wpre[4];
  int b = blockIdx.x, t = threadIdx.x;
  int i0 = b*512 + 2*t;
  int d0 = (i0     < N_NODES) ? deg[i0]     : 0;
  int d1 = (i0 + 1 < N_NODES) ? deg[i0 + 1] : 0;
  int s = d0 + d1;
  int incl = s;
  for (int o = 1; o < 64; o <<= 1){ int u = __shfl_up(incl, o); if ((t & 63) >= o) incl += u; }
  if ((t & 63) == 63) wpre[t >> 6] = incl;
  __syncthreads();
  if (t == 0){ int r = 0; for (int k = 0; k < 4; k++){ int x = wpre[k]; wpre[k] = r; r += x; } }
  __syncthreads();
  int excl = boff[b] + wpre[t >> 6] + incl - s;
  if (i0 < N_NODES){
    rp[i0] = excl; cursor[i0] = excl; degf[i0] = (float)d0;
  }
  if (i0 + 1 < N_NODES){
    rp[i0+1] = excl + d0; cursor[i0+1] = excl + d0; degf[i0+1] = (float)d1;
  }
}

// ---------------- wave ranges: wr[w] = first node with rp >= w*E/nw -------
__global__ void k_ranges(const int* __restrict__ rp, int* __restrict__ wr,
                         int nwaves){
  int w = blockIdx.x*blockDim.x + threadIdx.x;
  if (w > nwaves) return;
  if (w == nwaves){ wr[w] = N_NODES; return; }
  long long t0 = (long long)w * N_EDGES / nwaves;
  int lo = 0, hi = N_NODES;
  while (lo < hi){ int mid = (lo+hi)>>1; if ((long long)rp[mid] < t0) lo = mid+1; else hi = mid; }
  wr[w] = lo;
}

// ---------------- CSR scatter (fallback path: int2 perm2) ----------------
__global__ void k_scatter(const int* __restrict__ ei, int* __restrict__ cursor,
                          int* __restrict__ perm2){
  int i = blockIdx.x*blockDim.x + threadIdx.x;
  int stride = gridDim.x*blockDim.x;
  for (int e = i; e < N_EDGES; e += stride){
    int d = ei[N_EDGES + e];
    int p = atomicAdd(&cursor[d], 1);
    ((int2*)perm2)[p] = make_int2(ei[e], e);
  }
}

// ---------------- CSR scatter v2: perm (src only) + edge attrs permuted to
// CSR order as bf16.  REGULAR stores (r8: NT stores on random scatter = 3x
// write amplification, L2 coalescing is essential). ----
__global__ void k_scatter2(const int* __restrict__ ei, int* __restrict__ cursor,
                           int* __restrict__ perm, u16* __restrict__ eacsr,
                           const void* __restrict__ ea, const int* __restrict__ flagp){
  int isbf = *flagp;
  int i = blockIdx.x*blockDim.x + threadIdx.x;
  int stride = gridDim.x*blockDim.x;
  if (i < 16){
    perm[N_EDGES + i] = 0;
    uint4 z = make_uint4(0,0,0,0);
    uint4* out = (uint4*)(eacsr + (size_t)(N_EDGES + i)*16);
    out[0] = z; out[1] = z;
  }
  for (int e = i; e < N_EDGES; e += stride){
    int d = ei[N_EDGES + e];
    int p = atomicAdd(&cursor[d], 1);
    perm[p] = ei[e];
    uint4 r0, r1;
    if (isbf){
      const uint4* er = (const uint4*)((const u16*)ea + (size_t)e*16);
      r0 = er[0]; r1 = er[1];
    } else {
      const float4* ef = (const float4*)((const float*)ea + (size_t)e*16);
      float4 f0 = ef[0], f1 = ef[1], f2 = ef[2], f3 = ef[3];
      r0.x = (u32)f2bf(f0.x) | ((u32)f2bf(f0.y)<<16);
      r0.y = (u32)f2bf(f0.z) | ((u32)f2bf(f0.w)<<16);
      r0.z = (u32)f2bf(f1.x) | ((u32)f2bf(f1.y)<<16);
      r0.w = (u32)f2bf(f1.z) | ((u32)f2bf(f1.w)<<16);
      r1.x = (u32)f2bf(f2.x) | ((u32)f2bf(f2.y)<<16);
      r1.y = (u32)f2bf(f2.z) | ((u32)f2bf(f2.w)<<16);
      r1.z = (u32)f2bf(f3.x) | ((u32)f2bf(f3.y)<<16);
      r1.w = (u32)f2bf(f3.z) | ((u32)f2bf(f3.w)<<16);
    }
    uint4* out = (uint4*)(eacsr + (size_t)p*16);
    out[0] = r0; out[1] = r1;
  }
}

// tile-advance: next 16-edge tile after (ni, bi, ei); skips empty nodes.
__device__ __forceinline__ void adv_tile(const int* __restrict__ rp,
                                         int ni, int bi, int ei,
                                         int& no, int& bo, int& eo){
  if (bi + 16 < ei){ no = ni; bo = bi + 16; eo = ei; return; }
  int t = ni + 1;
  int nb = ei;
  int ne = rp[(t < N_NODES) ? t + 1 : N_NODES];
  while (nb == ne && t + 1 < N_NODES){
    t++; nb = ne; ne = rp[t + 1];
  }
  no = t; bo = nb; eo = ne;
}

// ---------------- MFMA message kernel (old, fallback path) ----------------
__global__ void __launch_bounds__(256) k_msgmm(
    const u16* __restrict__ hsp, const void* __restrict__ ea,
    const int* __restrict__ rp, const int* __restrict__ perm2,
    const u16* __restrict__ Wl, u16* __restrict__ aggs,
    float* __restrict__ stats, const int* __restrict__ flagp,
    int nwaves){
  __shared__ float bs[128];
  int tid = threadIdx.x;
  if (tid < 128) bs[tid] = 0.f;
  __syncthreads();
  int isbf = *flagp;
  int lane = tid & 63, wv = tid >> 6;
  int w = blockIdx.x*4 + wv;
  long long t0 = (long long)w     * N_EDGES / nwaves;
  long long t1 = (long long)(w+1) * N_EDGES / nwaves;
  int lo = 0, hi = N_NODES;
  while (lo < hi){ int mid = (lo+hi)>>1; if ((long long)rp[mid] < t0) lo = mid+1; else hi = mid; }
  int n0 = lo, n1;
  if (w == nwaves-1) n1 = N_NODES;
  else {
    lo = 0; hi = N_NODES;
    while (lo < hi){ int mid = (lo+hi)>>1; if ((long long)rp[mid] < t1) lo = mid+1; else hi = mid; }
    n1 = lo;
  }
  int nn = lane & 15, kg = lane >> 4;
  bf16x8 B[3][4];
#pragma unroll
  for (int t = 0; t < 4; t++)
#pragma unroll
    for (int kb = 0; kb < 3; kb++)
      B[kb][t] = *(const bf16x8*)(Wl + (size_t)(t*16+nn)*96 + kb*32 + kg*8);
  U4BF ac; ac.u = make_uint4((kg==2)? 0x3f80u : 0u, 0u, 0u, 0u);
  float s1[4] = {0,0,0,0}, s2[4] = {0,0,0,0};
  for (int n = n0; n < n1; n++){
    int b0 = rp[n], b1 = rp[n+1];
    float r0 = 0.f, r1 = 0.f, r2 = 0.f, r3 = 0.f;
    for (int base = b0; base < b1; base += 16){
      int rem = b1 - base; if (rem > 16) rem = 16;
      int row = (nn < rem) ? nn : rem-1;
      int2 p = ((const int2*)perm2)[base + row];
      const uint4* hp = (const uint4*)(hsp + (size_t)p.x*128);
      U4BF fA, fB, fC;
      fA.u = hp[kg];
      fB.u = hp[4 + kg];
      if (kg < 2){
        if (isbf){
          fC.u = ((const uint4*)ea)[(size_t)p.y*2 + kg];
        } else {
          const float4* ef = (const float4*)ea;
          float4 f0 = ef[(size_t)p.y*4 + kg*2];
          float4 f1 = ef[(size_t)p.y*4 + kg*2 + 1];
          fC.u.x = (u32)f2bf(f0.x) | ((u32)f2bf(f0.y)<<16);
          fC.u.y = (u32)f2bf(f0.z) | ((u32)f2bf(f0.w)<<16);
          fC.u.z = (u32)f2bf(f1.x) | ((u32)f2bf(f1.y)<<16);
          fC.u.w = (u32)f2bf(f1.z) | ((u32)f2bf(f1.w)<<16);
        }
      } else fC = ac;
      f32x4 a0 = {0,0,0,0}, a1 = {0,0,0,0}, a2 = {0,0,0,0}, a3 = {0,0,0,0};
      a0 = __builtin_amdgcn_mfma_f32_16x16x32_bf16(fA.v, B[0][0], a0, 0,0,0);
      a1 = __builtin_amdgcn_mfma_f32_16x16x32_bf16(fA.v, B[0][1], a1, 0,0,0);
      a2 = __builtin_amdgcn_mfma_f32_16x16x32_bf16(fA.v, B[0][2], a2, 0,0,0);
      a3 = __builtin_amdgcn_mfma_f32_16x16x32_bf16(fA.v, B[0][3], a3, 0,0,0);
      a0 = __builtin_amdgcn_mfma_f32_16x16x32_bf16(fB.v, B[1][0], a0, 0,0,0);
      a1 = __builtin_amdgcn_mfma_f32_16x16x32_bf16(fB.v, B[1][1], a1, 0,0,0);
      a2 = __builtin_amdgcn_mfma_f32_16x16x32_bf16(fB.v, B[1][2], a2, 0,0,0);
      a3 = __builtin_amdgcn_mfma_f32_16x16x32_bf16(fB.v, B[1][3], a3, 0,0,0);
      a0 = __builtin_amdgcn_mfma_f32_16x16x32_bf16(fC.v, B[2][0], a0, 0,0,0);
      a1 = __builtin_amdgcn_mfma_f32_16x16x32_bf16(fC.v, B[2][1], a1, 0,0,0);
      a2 = __builtin_amdgcn_mfma_f32_16x16x32_bf16(fC.v, B[2][2], a2, 0,0,0);
      a3 = __builtin_amdgcn_mfma_f32_16x16x32_bf16(fC.v, B[2][3], a3, 0,0,0);
      int rowbase = kg*4;
      float ts0 = 0.f, ts1 = 0.f, ts2 = 0.f, ts3 = 0.f;
#pragma unroll
      for (int j = 0; j < 4; j++){
        bool valid = (rowbase + j) < rem;
        float m0 = fmaxf(a0[j], 0.f); m0 = valid ? m0 : 0.f;
        float m1 = fmaxf(a1[j], 0.f); m1 = valid ? m1 : 0.f;
        float m2 = fmaxf(a2[j], 0.f); m2 = valid ? m2 : 0.f;
        float m3 = fmaxf(a3[j], 0.f); m3 = valid ? m3 : 0.f;
        ts0 += m0; ts1 += m1; ts2 += m2; ts3 += m3;
        s2[0] = fmaf(m0,m0,s2[0]); s2[1] = fmaf(m1,m1,s2[1]);
        s2[2] = fmaf(m2,m2,s2[2]); s2[3] = fmaf(m3,m3,s2[3]);
      }
      s1[0] += ts0; s1[1] += ts1; s1[2] += ts2; s1[3] += ts3;
      ts0 += __shfl_xor(ts0,16); ts0 += __shfl_xor(ts0,32);
      ts1 += __shfl_xor(ts1,16); ts1 += __shfl_xor(ts1,32);
      ts2 += __shfl_xor(ts2,16); ts2 += __shfl_xor(ts2,32);
      ts3 += __shfl_xor(ts3,16); ts3 += __shfl_xor(ts3,32);
      r0 += ts0; r1 += ts1; r2 += ts2; r3 += ts3;
    }
    float v = (kg==0) ? r0 : (kg==1) ? r1 : (kg==2) ? r2 : r3;
    u16 hiv = f2bf(v);
    aggs[(size_t)n*128 + lane]      = hiv;
    aggs[(size_t)n*128 + 64 + lane] = f2bf(v - bf2f(hiv));
  }
#pragma unroll
  for (int t = 0; t < 4; t++){
    atomicAdd(&bs[t*16+nn], s1[t]);
    atomicAdd(&bs[64+t*16+nn], s2[t]);
  }
  __syncthreads();
  if (tid < 128) atomicAdd(&stats[tid], bs[tid]);
}

// ---------------- MFMA message kernel v2: 2-stage pipeline +
// NT loads on single-use streams (perm, eacsr); precomputed wave ranges.
__global__ void __launch_bounds__(256) k_msgmm2(
    const u16* __restrict__ hsp, const u16* __restrict__ eacsr,
    const int* __restrict__ rp, const int* __restrict__ perm,
    const u16* __restrict__ Wl, u16* __restrict__ aggs,
    float* __restrict__ stats, const int* __restrict__ wranges){
  __shared__ float bs[128];
  int tid = threadIdx.x;
  if (tid < 128) bs[tid] = 0.f;
  __syncthreads();
  int lane = tid & 63;
  int w = blockIdx.x*4 + (tid >> 6);
  int nBeg = wranges[w], nEnd = wranges[w+1];
  int nn = lane & 15, kg = lane >> 4;
  bf16x8 B[3][4];
#pragma unroll
  for (int t = 0; t < 4; t++)
#pragma unroll
    for (int kb = 0; kb < 3; kb++)
      B[kb][t] = *(const bf16x8*)(Wl + (size_t)(t*16+nn)*96 + kb*32 + kg*8);
  U4BF ac; ac.u = make_uint4((kg==2)? 0x3f80u : 0u, 0u, 0u, 0u);
  float s1[4] = {0,0,0,0}, s2[4] = {0,0,0,0};

  if (nBeg < nEnd){
    // pre-pass: zero rows of empty nodes (rare; main walk skips them)
    {
      int pv = rp[nBeg];
      for (int m = nBeg; m < nEnd; m++){
        int nx = rp[m+1];
        if (nx == pv){
          aggs[(size_t)m*128 + lane] = 0;
          aggs[(size_t)m*128 + 64 + lane] = 0;
        }
        pv = nx;
      }
    }
    // initial tile: first non-empty node
    int nA = nBeg;
    int baseA = rp[nA], b1A = rp[nA+1];
    while (baseA == b1A && nA + 1 < nEnd){ nA++; baseA = b1A; b1A = rp[nA+1]; }
    if (baseA < b1A){
      int nB, baseB, b1B;
      adv_tile(rp, nA, baseA, b1A, nB, baseB, b1B);
      int pB = __builtin_nontemporal_load(&perm[baseB + nn]);
      // prologue loads for tile A
      U4BF fAA, fAB, fAC;
      {
        int pA = __builtin_nontemporal_load(&perm[baseA + nn]);
        const uint4* hpA = (const uint4*)(hsp + (size_t)pA*128);
        fAA.u = hpA[kg]; fAB.u = hpA[4 + kg];
        if (kg < 2) fAC.u = ntload4(eacsr + ((size_t)baseA + nn)*16 + (size_t)kg*8);
        else fAC = ac;
      }
      float r0 = 0.f, r1 = 0.f, r2 = 0.f, r3 = 0.f;
      while (true){
        // coords for t+2, prefetch its perm
        int nC, baseC, b1C;
        adv_tile(rp, nB, baseB, b1B, nC, baseC, b1C);
        int pC = __builtin_nontemporal_load(&perm[baseC + nn]);
        // prefetch tile B operands (overlap with MFMA of tile A)
        const uint4* hpB = (const uint4*)(hsp + (size_t)pB*128);
        U4BF fBA, fBB, fBC;
        fBA.u = hpB[kg]; fBB.u = hpB[4 + kg];
        if (kg < 2) fBC.u = ntload4(eacsr + ((size_t)baseB + nn)*16 + (size_t)kg*8);
        else fBC = ac;
        // MFMA on tile A
        f32x4 a0 = {0,0,0,0}, a1 = {0,0,0,0}, a2 = {0,0,0,0}, a3 = {0,0,0,0};
        a0 = __builtin_amdgcn_mfma_f32_16x16x32_bf16(fAA.v, B[0][0], a0, 0,0,0);
        a1 = __builtin_amdgcn_mfma_f32_16x16x32_bf16(fAA.v, B[0][1], a1, 0,0,0);
        a2 = __builtin_amdgcn_mfma_f32_16x16x32_bf16(fAA.v, B[0][2], a2, 0,0,0);
        a3 = __builtin_amdgcn_mfma_f32_16x16x32_bf16(fAA.v, B[0][3], a3, 0,0,0);
        a0 = __builtin_amdgcn_mfma_f32_16x16x32_bf16(fAB.v, B[1][0], a0, 0,0,0);
        a1 = __builtin_amdgcn_mfma_f32_16x16x32_bf16(fAB.v, B[1][1], a1, 0,0,0);
        a2 = __builtin_amdgcn_mfma_f32_16x16x32_bf16(fAB.v, B[1][2], a2, 0,0,0);
        a3 = __builtin_amdgcn_mfma_f32_16x16x32_bf16(fAB.v, B[1][3], a3, 0,0,0);
        a0 = __builtin_amdgcn_mfma_f32_16x16x32_bf16(fAC.v, B[2][0], a0, 0,0,0);
        a1 = __builtin_amdgcn_mfma_f32_16x16x32_bf16(fAC.v, B[2][1], a1, 0,0,0);
        a2 = __builtin_amdgcn_mfma_f32_16x16x32_bf16(fAC.v, B[2][2], a2, 0,0,0);
        a3 = __builtin_amdgcn_mfma_f32_16x16x32_bf16(fAC.v, B[2][3], a3, 0,0,0);
        // epilogue for tile A
        int rem = b1A - baseA; if (rem > 16) rem = 16;
        int rowbase = kg*4;
        float ts0 = 0.f, ts1 = 0.f, ts2 = 0.f, ts3 = 0.f;
#pragma unroll
        for (int j = 0; j < 4; j++){
          bool valid = (rowbase + j) < rem;
          float m0 = fmaxf(a0[j], 0.f); m0 = valid ? m0 : 0.f;
          float m1 = fmaxf(a1[j], 0.f); m1 = valid ? m1 : 0.f;
          float m2 = fmaxf(a2[j], 0.f); m2 = valid ? m2 : 0.f;
          float m3 = fmaxf(a3[j], 0.f); m3 = valid ? m3 : 0.f;
          ts0 += m0; ts1 += m1; ts2 += m2; ts3 += m3;
          s2[0] = fmaf(m0,m0,s2[0]); s2[1] = fmaf(m1,m1,s2[1]);
          s2[2] = fmaf(m2,m2,s2[2]); s2[3] = fmaf(m3,m3,s2[3]);
        }
        s1[0] += ts0; s1[1] += ts1; s1[2] += ts2; s1[3] += ts3;
        r0 += ts0; r1 += ts1; r2 += ts2; r3 += ts3;
        if (baseA + 16 >= b1A){          // last tile of node nA
          r0 += __shfl_xor(r0,16); r0 += __shfl_xor(r0,32);
          r1 += __shfl_xor(r1,16); r1 += __shfl_xor(r1,32);
          r2 += __shfl_xor(r2,16); r2 += __shfl_xor(r2,32);
          r3 += __shfl_xor(r3,16); r3 += __shfl_xor(r3,32);
          float v = (kg==0) ? r0 : (kg==1) ? r1 : (kg==2) ? r2 : r3;
          u16 hiv = f2bf(v);
          aggs[(size_t)nA*128 + lane]      = hiv;
          aggs[(size_t)nA*128 + 64 + lane] = f2bf(v - bf2f(hiv));
          r0 = r1 = r2 = r3 = 0.f;
        }
        // rotate pipeline
        nA = nB; baseA = baseB; b1A = b1B;
        fAA = fBA; fAB = fBB; fAC = fBC;
        nB = nC; baseB = baseC; b1B = b1C; pB = pC;
        if (nA >= nEnd) break;
      }
    }
  }
#pragma unroll
  for (int t = 0; t < 4; t++){
    atomicAdd(&bs[t*16+nn], s1[t]);
    atomicAdd(&bs[64+t*16+nn], s2[t]);
  }
  __syncthreads();
  if (tid < 128) atomicAdd(&stats[tid], bs[tid]);
}

// ---------------- BN finalize (self-zeroes stats) ----------------
__global__ void k_fin(float* __restrict__ stats, const void* __restrict__ gamma,
                      const void* __restrict__ beta, float* __restrict__ aff,
                      float cnt_inv, int goff, const int* __restrict__ flagp){
  int isbf = *flagp; int c = threadIdx.x;
  float mu  = stats[c]      * cnt_inv;
  float var = stats[64 + c] * cnt_inv - mu*mu;
  float rs  = rsqrtf(var + 1e-5f);
  float g = ldf(gamma, (size_t)goff + c, isbf);
  float b = ldf(beta,  (size_t)goff + c, isbf);
  aff[c]      = g*rs;
  aff[64 + c] = b - g*mu*rs;
  stats[c] = 0.f; stats[64 + c] = 0.f;
}

// ---------------- MFMA fused update, split-precision ----------------
// h input is PRE-BN (haff folded into Wa via updprep); agg in G; writes
// pre-BN relu(u) split hi/lo IN PLACE over G (wave owns its 16 rows).
// Both inputs are LAST-USE streams here -> NT loads (protect gather set).
#define UPD_TILES (N_NODES/16)
__global__ void __launch_bounds__(256) k_updmm(
    const u16* __restrict__ hsp, u16* __restrict__ aggs,
    const float* __restrict__ degf, const u16* __restrict__ Wupd,
    const float* __restrict__ biasv, const float* __restrict__ tvv,
    float* __restrict__ stats){
  __shared__ float bs[128];
  int tid = threadIdx.x;
  if (tid < 128) bs[tid] = 0.f;
  __syncthreads();
  int lane = tid & 63;
  int nn = lane & 15, kg = lane >> 4;
  int w = blockIdx.x*4 + (tid >> 6);
  int nwv = gridDim.x*4;
  bf16x8 B[6][4];
#pragma unroll
  for (int t = 0; t < 4; t++)
#pragma unroll
    for (int kb = 0; kb < 6; kb++)
      B[kb][t] = *(const bf16x8*)(Wupd + (size_t)(t*16+nn)*192 + kb*32 + kg*8);
  float bc[4], tc[4];
#pragma unroll
  for (int t = 0; t < 4; t++){ bc[t] = biasv[t*16+nn]; tc[t] = tvv[t*16+nn]; }
  float s1[4] = {0,0,0,0}, s2[4] = {0,0,0,0};
  for (int tile = w; tile < UPD_TILES; tile += nwv){
    int n0 = tile*16;
    int r = n0 + nn;
    const uint4* hp = (const uint4*)hsp;
    const uint4* ap = (const uint4*)aggs;
    U4BF hh0, hh1, hl0, hl1, ah0, ah1, al0, al1;
    hh0.u = ntload4(&hp[(size_t)r*16 + kg]);       hh1.u = ntload4(&hp[(size_t)r*16 + 4 + kg]);
    hl0.u = ntload4(&hp[(size_t)r*16 + 8 + kg]);   hl1.u = ntload4(&hp[(size_t)r*16 + 12 + kg]);
    ah0.u = ntload4(&ap[(size_t)r*16 + kg]);       ah1.u = ntload4(&ap[(size_t)r*16 + 4 + kg]);
    al0.u = ntload4(&ap[(size_t)r*16 + 8 + kg]);   al1.u = ntload4(&ap[(size_t)r*16 + 12 + kg]);
    float dg[4];
#pragma unroll
    for (int j = 0; j < 4; j++) dg[j] = degf[n0 + kg*4 + j];
    f32x4 a0 = {0,0,0,0}, a1 = {0,0,0,0}, a2 = {0,0,0,0}, a3 = {0,0,0,0};
#define MF(F,KB) \
    a0 = __builtin_amdgcn_mfma_f32_16x16x32_bf16(F.v, B[KB][0], a0, 0,0,0); \
    a1 = __builtin_amdgcn_mfma_f32_16x16x32_bf16(F.v, B[KB][1], a1, 0,0,0); \
    a2 = __builtin_amdgcn_mfma_f32_16x16x32_bf16(F.v, B[KB][2], a2, 0,0,0); \
    a3 = __builtin_amdgcn_mfma_f32_16x16x32_bf16(F.v, B[KB][3], a3, 0,0,0);
    MF(hh0,0) MF(hh1,1) MF(hl0,0) MF(hl1,1)
    MF(ah0,2) MF(ah1,3) MF(ah0,4) MF(ah1,5)
    MF(al0,2) MF(al1,3)
#undef MF
#pragma unroll
    for (int j = 0; j < 4; j++){
      int n = n0 + kg*4 + j;
      float m0 = fmaxf(fmaf(tc[0], dg[j], a0[j] + bc[0]), 0.f);
      float m1 = fmaxf(fmaf(tc[1], dg[j], a1[j] + bc[1]), 0.f);
      float m2 = fmaxf(fmaf(tc[2], dg[j], a2[j] + bc[2]), 0.f);
      float m3 = fmaxf(fmaf(tc[3], dg[j], a3[j] + bc[3]), 0.f);
      s1[0] += m0; s1[1] += m1; s1[2] += m2; s1[3] += m3;
      s2[0] = fmaf(m0,m0,s2[0]); s2[1] = fmaf(m1,m1,s2[1]);
      s2[2] = fmaf(m2,m2,s2[2]); s2[3] = fmaf(m3,m3,s2[3]);
      u16* hw = aggs + (size_t)n*128;
      u16 q0 = f2bf(m0), q1 = f2bf(m1), q2 = f2bf(m2), q3 = f2bf(m3);
      hw[     nn] = q0;  hw[64 +      nn] = f2bf(m0 - bf2f(q0));
      hw[16 + nn] = q1;  hw[64 + 16 + nn] = f2bf(m1 - bf2f(q1));
      hw[32 + nn] = q2;  hw[64 + 32 + nn] = f2bf(m2 - bf2f(q2));
      hw[48 + nn] = q3;  hw[64 + 48 + nn] = f2bf(m3 - bf2f(q3));
    }
  }
#pragma unroll
  for (int t = 0; t < 4; t++){
    atomicAdd(&bs[t*16+nn], s1[t]);
    atomicAdd(&bs[64+t*16+nn], s2[t]);
  }
  __syncthreads();
  if (tid < 128) atomicAdd(&stats[tid], bs[tid]);
}

// ---------------- global add pool over PRE-BN h with affine applied:
// g[b] = s * sum(u) + t * count(b) ----------------
__global__ void k_pool(const u16* __restrict__ hsp, const int* __restrict__ batch,
                       const float* __restrict__ aff, float* __restrict__ g){
  int lane = threadIdx.x & 63;
  int gw = (blockIdx.x*blockDim.x + threadIdx.x) >> 6;
  int nw = (gridDim.x*blockDim.x) >> 6;
  float s = aff[lane], t = aff[64 + lane];
  int chunk = (N_NODES + nw - 1) / nw;
  int n0 = gw*chunk;
  int n1 = n0 + chunk; if (n1 > N_NODES) n1 = N_NODES;
  int cur = -1; float acc = 0.f, cnt = 0.f;
  for (int n = n0; n < n1; n++){
    int b = batch[n];
    float v = bf2f(hsp[(size_t)n*128 + lane]) + bf2f(hsp[(size_t)n*128 + 64 + lane]);
    if (b != cur){
      if (cur >= 0) atomicAdd(&g[(size_t)cur*64 + lane], fmaf(s, acc, t*cnt));
      cur = b; acc = v; cnt = 1.f;
    } else { acc += v; cnt += 1.f; }
  }
  if (cur >= 0) atomicAdd(&g[(size_t)cur*64 + lane], fmaf(s, acc, t*cnt));
}

// ---------------- readout ----------------
__global__ void k_read(const float* __restrict__ g, const void* __restrict__ r1W,
                       const void* __restrict__ r1b, const void* __restrict__ r2W,
                       const void* __restrict__ r2b, void* __restrict__ out,
                       const int* __restrict__ flagp){
  int isbf = *flagp;
  int lane = threadIdx.x;
  int gr = blockIdx.x;
  float w[64];
#pragma unroll
  for (int k = 0; k < 64; k++) w[k] = ldf(r1W, (size_t)k*64 + lane, isbf);
  float acc = ldf(r1b, lane, isbf);
  const float4* grow = (const float4*)(g + (size_t)gr*64);
#pragma unroll
  for (int q = 0; q < 16; q++){
    float4 a = grow[q];
    acc = fmaf(a.x, w[4*q+0], acc); acc = fmaf(a.y, w[4*q+1], acc);
    acc = fmaf(a.z, w[4*q+2], acc); acc = fmaf(a.w, w[4*q+3], acc);
  }
  float hid = fmaxf(acc, 0.f);
  float p = hid * ldf(r2W, lane, isbf);
  for (int o = 32; o; o >>= 1) p += __shfl_xor(p, o);
  if (lane == 0){
    float v = p + ldf(r2b, 0, isbf);
    if (isbf) ((__hip_bfloat16*)out)[gr] = __float2bfloat16(v);
    else      ((float*)out)[gr] = v;
  }
}

extern "C" void kernel_launch(void* const* d_in, const int* in_sizes, int n_in,
                              void* d_out, int out_size, void* d_ws, size_t ws_size,
                              hipStream_t stream){
  const void* x    = d_in[0];
  const void* ea   = d_in[1];
  const int*  ei   = (const int*)d_in[2];
  const int*  bt   = (const int*)d_in[3];
  const void* nW   = d_in[4];  const void* nb  = d_in[5];
  const void* eW   = d_in[6];  const void* eb  = d_in[7];
  const void* mW   = d_in[8];  const void* mb  = d_in[9];
  const void* mg   = d_in[10]; const void* mbe = d_in[11];
  const void* uW   = d_in[12]; const void* ub  = d_in[13];
  const void* ug   = d_in[14]; const void* ube = d_in[15];
  const void* r1W  = d_in[16]; const void* r1b = d_in[17];
  const void* r2W  = d_in[18]; const void* r2b = d_in[19];

  // big path needs 27,692,011 floats = 110,768,044 bytes
  const size_t NEED_BIG = 110768044ull;
  const bool big = (ws_size >= NEED_BIG);

  float* ws = (float*)d_ws;
  size_t off = 0;
  auto alloc = [&](size_t n){ float* p = ws + off; off += n; return p; };

  u16*   hsp   = (u16*)alloc(6400000);
  u16*   aggs  = (u16*)alloc(6400000);
  u16*   eacsr = nullptr; int* perm = nullptr; int* perm2 = nullptr;
  if (big){
    eacsr = (u16*)alloc(12800128);          // (E+16) rows x 16 u16
    perm  = (int*)alloc(1600016);           // E+16 ints
  } else {
    perm2 = (int*)alloc(3200000);           // E int2
  }
  float* degf   = alloc(100000);
  float* zero0  = ws + off;                 // memset region start
  int*   deg_i  = (int*)alloc(100000);
  float* g      = alloc(64000);
  float* mstats = alloc(128);
  float* ustats = alloc(128);
  size_t zeroN  = (size_t)((ws + off) - zero0);   // 164,256 floats
  float* maff   = alloc(128);
  float* haff   = alloc(128);
  int*   flag   = (int*)alloc(16);
  u16*   Weff   = (u16*)alloc(9216);        // base msg weights (3 layers)
  u16*   Wfold  = (u16*)alloc(3072);        // per-layer folded msg weights
  u16*   Wupd   = (u16*)alloc(6144);
  float* biasm  = alloc(192);               // f32 base msg bias (3 layers)
  float* biasv  = alloc(64);
  float* tvv    = alloc(64);
  int*   row_ptr= (int*)alloc(100001);
  int*   cursor = (int*)alloc(100000);
  int*   bsum   = (int*)alloc(196);
  int*   boff   = (int*)alloc(196);
  int*   wrng   = (int*)alloc(8194);        // wave ranges (MM_WAVES+1)

  const int MM_BLOCKS = 2048;
  const int MM_WAVES  = MM_BLOCKS * 4;
  const int UPD_BLOCKS = 782;

  k_detect<<<1, 64, 0, stream>>>((const u32*)x, flag);
  hipMemsetAsync(zero0, 0, zeroN*sizeof(float), stream);
  k_idaff<<<1, 64, 0, stream>>>(haff);
  k_prep<<<3, 64, 0, stream>>>(eW, eb, mW, mb, Weff, biasm, flag);
  k_node_emb<<<256, 256, 0, stream>>>(x, nW, nb, hsp, flag);
  k_deg<<<512, 256, 0, stream>>>(ei, deg_i);
  k_scan1<<<196, 256, 0, stream>>>(deg_i, bsum);
  k_scan2<<<1, 256, 0, stream>>>(bsum, boff, row_ptr);
  k_scan3<<<196, 256, 0, stream>>>(deg_i, boff, row_ptr, cursor, degf);
  if (big){
    k_ranges<<<33, 256, 0, stream>>>(row_ptr, wrng, MM_WAVES);
    k_scatter2<<<512, 256, 0, stream>>>(ei, cursor, perm, eacsr, ea, flag);
  } else {
    k_scatter<<<512, 256, 0, stream>>>(ei, cursor, perm2);
  }

  u16* H = hsp;   // current h (layer 0: embedding; l>0: pre-BN relu(u), haff pending)
  u16* G = aggs;  // scratch: msg agg, then overwritten by pre-BN relu(u)
  for (int l = 0; l < 3; l++){
    k_fold<<<1, 64, 0, stream>>>(mW, Weff, biasm, haff, Wfold, flag, l);
    if (big)
      k_msgmm2<<<MM_BLOCKS, 256, 0, stream>>>(H, eacsr, row_ptr, perm, Wfold,
                                              G, mstats, wrng);
    else
      k_msgmm<<<MM_BLOCKS, 256, 0, stream>>>(H, ea, row_ptr, perm2, Wfold,
                                             G, mstats, flag, MM_WAVES);
    k_fin<<<1, 64, 0, stream>>>(mstats, mg, mbe, maff, 1.0f/(float)N_EDGES, l*64, flag);
    k_updprep<<<1, 64, 0, stream>>>(uW, ub, maff, haff, Wupd, biasv, tvv, flag, l);
    k_updmm<<<UPD_BLOCKS, 256, 0, stream>>>(H, G, degf, Wupd, biasv, tvv, ustats);
    k_fin<<<1, 64, 0, stream>>>(ustats, ug, ube, haff, 1.0f/(float)N_NODES, l*64, flag);
    u16* tmp = H; H = G; G = tmp;
  }

  k_pool<<<128, 256, 0, stream>>>(H, bt, haff, g);
  k_read<<<NUM_GRAPHS, 64, 0, stream>>>(g, r1W, r1b, r2W, r2b, d_out, flag);
}

// Round 14
// 1318.811 us; speedup vs baseline: 1.0714x; 1.0373x over previous
//
#include <hip/hip_runtime.h>
#include <hip/hip_bf16.h>

#define N_NODES   100000
#define N_EDGES   1600000
#define NUM_GRAPHS 1000

typedef unsigned int u32;
typedef unsigned short u16;

typedef __bf16 bf16_t;
typedef bf16_t bf16x8 __attribute__((ext_vector_type(8)));
typedef float  f32x4  __attribute__((ext_vector_type(4)));
typedef u32    u32x4  __attribute__((ext_vector_type(4)));

__device__ __forceinline__ float bf2f(u16 u){ return __uint_as_float(((u32)u)<<16); }
__device__ __forceinline__ float BL(u32 u){ return __uint_as_float(u<<16); }
__device__ __forceinline__ float BH(u32 u){ return __uint_as_float(u&0xffff0000u); }
// f32 -> bf16 bits, round-to-nearest-even
__device__ __forceinline__ u16 f2bf(float f){
  u32 u = __float_as_uint(f);
  return (u16)((u + 0x7fffu + ((u>>16)&1u)) >> 16);
}
// dual-dtype scalar load: isbf=1 -> bf16, else f32
__device__ __forceinline__ float ldf(const void* p, size_t i, int isbf){
  return isbf ? bf2f(((const u16*)p)[i]) : ((const float*)p)[i];
}
// non-temporal 16B load. r8: NT stores on random scatter = 3x write amp (BAD).
// r12: NT loads on msgmm streams RAISED FETCH 121.7->130MB (L3 bypass) - dropped
// there; kept only in k_updmm (last-use streaming reads).
__device__ __forceinline__ uint4 ntload4(const void* p){
  u32x4 v = __builtin_nontemporal_load((const u32x4*)p);
  return make_uint4(v.x, v.y, v.z, v.w);
}

union U4BF { uint4 u; bf16x8 v; };

// ---------------- dtype detector ----------------
__global__ void k_detect(const u32* __restrict__ x, int* __restrict__ flag){
  int t = threadIdx.x; int cnt = 0;
  for (int i = t; i < 256; i += 64){
    u32 w = x[i];
    u32 e = (w >> 7) & 0xffu;
    if (e >= 110u && e <= 137u) cnt++;
  }
  for (int o = 32; o; o >>= 1) cnt += __shfl_xor(cnt, o);
  if (t == 0) *flag = (cnt > 128) ? 1 : 0;
}

// ---------------- identity affine init: s=1, t=0 ----------------
__global__ void k_idaff(float* __restrict__ haff){
  int c = threadIdx.x;
  haff[c] = 1.f; haff[64 + c] = 0.f;
}

// ---------------- weight prep: base Weff[l][c][96] + f32 base bias ---------
__global__ void k_prep(const void* __restrict__ eW, const void* __restrict__ eb,
                       const void* __restrict__ mW, const void* __restrict__ mb,
                       u16* __restrict__ Weff, float* __restrict__ biasm,
                       const int* __restrict__ flagp){
  int isbf = *flagp;
  int l = blockIdx.x, c = threadIdx.x;
  u16* W = Weff + ((size_t)l*64 + c)*96;
  for (int k = 0; k < 64; k++)
    W[k] = f2bf(ldf(mW, (size_t)(l*96 + k)*64 + c, isbf));
  for (int j = 0; j < 16; j++){
    float acc = 0.f;
    for (int k = 0; k < 32; k++)
      acc += ldf(eW, (size_t)j*32 + k, isbf) * ldf(mW, (size_t)(l*96 + 64 + k)*64 + c, isbf);
    W[64 + j] = f2bf(acc);
  }
  float fbv = ldf(mb, (size_t)l*64 + c, isbf);
  for (int k = 0; k < 32; k++)
    fbv += ldf(eb, k, isbf) * ldf(mW, (size_t)(l*96 + 64 + k)*64 + c, isbf);
  W[80] = f2bf(fbv);
  biasm[(size_t)l*64 + c] = fbv;
  for (int k = 81; k < 96; k++) W[k] = 0;
}

// ---------------- per-layer msg-weight fold ----------------
__global__ void k_fold(const void* __restrict__ mW, const u16* __restrict__ Wbase,
                       const float* __restrict__ biasm, const float* __restrict__ haff,
                       u16* __restrict__ Wf, const int* __restrict__ flagp, int l){
  int isbf = *flagp; int c = threadIdx.x;
  const u16* Wb = Wbase + ((size_t)l*64 + c)*96;
  u16* W = Wf + (size_t)c*96;
  float bb = biasm[(size_t)l*64 + c];
  for (int k = 0; k < 64; k++){
    float w = ldf(mW, (size_t)(l*96 + k)*64 + c, isbf);
    W[k] = f2bf(haff[k] * w);
    bb = fmaf(haff[64 + k], w, bb);
  }
  for (int k = 64; k < 80; k++) W[k] = Wb[k];
  W[80] = f2bf(bb);
  for (int k = 81; k < 96; k++) W[k] = 0;
}

// ---------------- update-weight prep ----------------
__global__ void k_updprep(const void* __restrict__ uW, const void* __restrict__ ub,
                          const float* __restrict__ maff, const float* __restrict__ haff,
                          u16* __restrict__ Wupd, float* __restrict__ biasv,
                          float* __restrict__ tvv, const int* __restrict__ flagp, int l){
  int isbf = *flagp; int c = threadIdx.x;
  u16* W = Wupd + (size_t)c*192;
  float tv = 0.f, bb = 0.f;
  for (int k = 0; k < 64; k++){
    float wka = ldf(uW, (size_t)(l*128 + k)*64 + c, isbf);
    W[k] = f2bf(haff[k] * wka);
    bb = fmaf(haff[64 + k], wka, bb);
    float wkb = ldf(uW, (size_t)(l*128 + 64 + k)*64 + c, isbf);
    float prod = wkb * maff[k];
    u16 hi = f2bf(prod);
    W[64 + k]  = hi;
    W[128 + k] = f2bf(prod - bf2f(hi));
    tv = fmaf(maff[64 + k], wkb, tv);
  }
  biasv[c] = ldf(ub, (size_t)l*64 + c, isbf) + bb;
  tvv[c] = tv;
}

// ---------------- node embedding -> hsp split hi/lo ----
__global__ void k_node_emb(const void* __restrict__ x, const void* __restrict__ nW,
                           const void* __restrict__ nb, u16* __restrict__ hsp,
                           const int* __restrict__ flagp){
  int isbf = *flagp;
  int lane = threadIdx.x & 63;
  int gw = (blockIdx.x*blockDim.x + threadIdx.x) >> 6;
  int nw = (gridDim.x*blockDim.x) >> 6;
  float w[32];
#pragma unroll
  for (int k = 0; k < 32; k++) w[k] = ldf(nW, (size_t)k*64 + lane, isbf);
  float bias = ldf(nb, lane, isbf);
  for (int n = gw; n < N_NODES; n += nw){
    float acc = bias;
    if (isbf){
      const uint4* xr = (const uint4*)((const u16*)x + (size_t)n*32);
#pragma unroll
      for (int q = 0; q < 4; q++){
        uint4 a = xr[q];
        u32 uu[4] = {a.x, a.y, a.z, a.w};
#pragma unroll
        for (int j = 0; j < 4; j++){
          acc = fmaf(BL(uu[j]), w[q*8 + 2*j + 0], acc);
          acc = fmaf(BH(uu[j]), w[q*8 + 2*j + 1], acc);
        }
      }
    } else {
      const float4* xr = (const float4*)((const float*)x + (size_t)n*32);
#pragma unroll
      for (int q = 0; q < 8; q++){
        float4 a = xr[q];
        acc = fmaf(a.x, w[q*4+0], acc); acc = fmaf(a.y, w[q*4+1], acc);
        acc = fmaf(a.z, w[q*4+2], acc); acc = fmaf(a.w, w[q*4+3], acc);
      }
    }
    u16 hi = f2bf(acc);
    hsp[(size_t)n*128 + lane]      = hi;
    hsp[(size_t)n*128 + 64 + lane] = f2bf(acc - bf2f(hi));
  }
}

// ---------------- in-degree histogram ----------------
__global__ void k_deg(const int* __restrict__ ei, int* __restrict__ deg){
  int i = blockIdx.x*blockDim.x + threadIdx.x;
  int stride = gridDim.x*blockDim.x;
  for (int e = i; e < N_EDGES; e += stride)
    atomicAdd(&deg[ei[N_EDGES + e]], 1);
}

// ---------------- multi-block scan: phase 1 ----------------
__global__ void __launch_bounds__(256) k_scan1(const int* __restrict__ deg,
                                               int* __restrict__ bsum){
  __shared__ int wsum[4];
  int b = blockIdx.x, t = threadIdx.x;
  int i0 = b*512 + t;
  int s = 0;
  if (i0 < N_NODES) s += deg[i0];
  if (i0 + 256 < N_NODES) s += deg[i0 + 256];
  for (int o = 32; o; o >>= 1) s += __shfl_xor(s, o);
  if ((t & 63) == 0) wsum[t >> 6] = s;
  __syncthreads();
  if (t == 0) bsum[b] = wsum[0] + wsum[1] + wsum[2] + wsum[3];
}

// ---------------- scan phase 2 ----------------
__global__ void k_scan2(const int* __restrict__ bsum, int* __restrict__ boff,
                        int* __restrict__ rp){
  __shared__ int l[200];
  int t = threadIdx.x;
  if (t < 196) l[t] = bsum[t];
  __syncthreads();
  if (t == 0){
    int r = 0;
    for (int k = 0; k < 196; k++){ int x = l[k]; l[k] = r; r += x; }
    rp[N_NODES] = r;
  }
  __syncthreads();
  if (t < 196) boff[t] = l[t];
}

// ---------------- scan phase 3 ----------------
__global__ void __launch_bounds__(256) k_scan3(const int* __restrict__ deg,
                        const int* __restrict__ boff, int* __restrict__ rp,
                        int* __restrict__ cursor, float* __restrict__ degf){
  __shared__ int wpre[4];
  int b = blockIdx.x, t = threadIdx.x;
  int i0 = b*512 + 2*t;
  int d0 = (i0     < N_NODES) ? deg[i0]     : 0;
  int d1 = (i0 + 1 < N_NODES) ? deg[i0 + 1] : 0;
  int s = d0 + d1;
  int incl = s;
  for (int o = 1; o < 64; o <<= 1){ int u = __shfl_up(incl, o); if ((t & 63) >= o) incl += u; }
  if ((t & 63) == 63) wpre[t >> 6] = incl;
  __syncthreads();
  if (t == 0){ int r = 0; for (int k = 0; k < 4; k++){ int x = wpre[k]; wpre[k] = r; r += x; } }
  __syncthreads();
  int excl = boff[b] + wpre[t >> 6] + incl - s;
  if (i0 < N_NODES){
    rp[i0] = excl; cursor[i0] = excl; degf[i0] = (float)d0;
  }
  if (i0 + 1 < N_NODES){
    rp[i0+1] = excl + d0; cursor[i0+1] = excl + d0; degf[i0+1] = (float)d1;
  }
}

// ---------------- wave ranges: wr[w] = first node with rp >= w*E/nw -------
__global__ void k_ranges(const int* __restrict__ rp, int* __restrict__ wr,
                         int nwaves){
  int w = blockIdx.x*blockDim.x + threadIdx.x;
  if (w > nwaves) return;
  if (w == nwaves){ wr[w] = N_NODES; return; }
  long long t0 = (long long)w * N_EDGES / nwaves;
  int lo = 0, hi = N_NODES;
  while (lo < hi){ int mid = (lo+hi)>>1; if ((long long)rp[mid] < t0) lo = mid+1; else hi = mid; }
  wr[w] = lo;
}

// ---------------- flat tile list (r13): removes the serial rp-walk from the
// msgmm hot loop.  record = node<<5 | (rem-1)<<1 | last  (4B/tile; base is a
// running sum of rem starting at rp[wr[w]]).

// per-wave tile count
__global__ void k_tcnt(const int* __restrict__ rp, const int* __restrict__ wr,
                       int* __restrict__ tcnt, int nwaves){
  int w = blockIdx.x*blockDim.x + threadIdx.x;
  if (w >= nwaves) return;
  int n0 = wr[w], n1 = wr[w+1];
  int c = 0;
  for (int n = n0; n < n1; n++){
    int d = rp[n+1] - rp[n];
    c += (d + 15) >> 4;
  }
  tcnt[w] = c;
}

// exclusive scan of nwaves (=8192 = 256*32) counts -> twoff[0..nwaves]
__global__ void k_tscan(const int* __restrict__ tcnt, int* __restrict__ twoff,
                        int nwaves){
  __shared__ int ps[256];
  int t = threadIdx.x;
  int s = 0;
  for (int i = 0; i < 32; i++) s += tcnt[t*32 + i];
  ps[t] = s;
  __syncthreads();
  if (t == 0){
    int r = 0;
    for (int k = 0; k < 256; k++){ int x = ps[k]; ps[k] = r; r += x; }
    twoff[nwaves] = r;
  }
  __syncthreads();
  int off = ps[t];
  for (int i = 0; i < 32; i++){
    twoff[t*32 + i] = off;
    off += tcnt[t*32 + i];
  }
}

// fill tile records
__global__ void k_tfill(const int* __restrict__ rp, const int* __restrict__ wr,
                        const int* __restrict__ twoff, int* __restrict__ tlist,
                        int nwaves){
  int w = blockIdx.x*blockDim.x + threadIdx.x;
  if (w >= nwaves) return;
  int n0 = wr[w], n1 = wr[w+1];
  int o = twoff[w];
  for (int n = n0; n < n1; n++){
    int b = rp[n], e = rp[n+1];
    while (b < e){
      int rem = e - b; if (rem > 16) rem = 16;
      int last = (b + 16 >= e) ? 1 : 0;
      tlist[o++] = (n << 5) | ((rem - 1) << 1) | last;
      b += 16;
    }
  }
}

// ---------------- CSR scatter (fallback path: int2 perm2) ----------------
__global__ void k_scatter(const int* __restrict__ ei, int* __restrict__ cursor,
                          int* __restrict__ perm2){
  int i = blockIdx.x*blockDim.x + threadIdx.x;
  int stride = gridDim.x*blockDim.x;
  for (int e = i; e < N_EDGES; e += stride){
    int d = ei[N_EDGES + e];
    int p = atomicAdd(&cursor[d], 1);
    ((int2*)perm2)[p] = make_int2(ei[e], e);
  }
}

// ---------------- CSR scatter v2: perm (src only) + edge attrs permuted to
// CSR order as bf16.  REGULAR stores (r8: NT stores = 3x write amp).
// Pads 48 slots past E (covers depth-2 base lookahead of up to +32). ----
__global__ void k_scatter2(const int* __restrict__ ei, int* __restrict__ cursor,
                           int* __restrict__ perm, u16* __restrict__ eacsr,
                           const void* __restrict__ ea, const int* __restrict__ flagp){
  int isbf = *flagp;
  int i = blockIdx.x*blockDim.x + threadIdx.x;
  int stride = gridDim.x*blockDim.x;
  if (i < 48){
    perm[N_EDGES + i] = 0;
    uint4 z = make_uint4(0,0,0,0);
    uint4* out = (uint4*)(eacsr + (size_t)(N_EDGES + i)*16);
    out[0] = z; out[1] = z;
  }
  for (int e = i; e < N_EDGES; e += stride){
    int d = ei[N_EDGES + e];
    int p = atomicAdd(&cursor[d], 1);
    perm[p] = ei[e];
    uint4 r0, r1;
    if (isbf){
      const uint4* er = (const uint4*)((const u16*)ea + (size_t)e*16);
      r0 = er[0]; r1 = er[1];
    } else {
      const float4* ef = (const float4*)((const float*)ea + (size_t)e*16);
      float4 f0 = ef[0], f1 = ef[1], f2 = ef[2], f3 = ef[3];
      r0.x = (u32)f2bf(f0.x) | ((u32)f2bf(f0.y)<<16);
      r0.y = (u32)f2bf(f0.z) | ((u32)f2bf(f0.w)<<16);
      r0.z = (u32)f2bf(f1.x) | ((u32)f2bf(f1.y)<<16);
      r0.w = (u32)f2bf(f1.z) | ((u32)f2bf(f1.w)<<16);
      r1.x = (u32)f2bf(f2.x) | ((u32)f2bf(f2.y)<<16);
      r1.y = (u32)f2bf(f2.z) | ((u32)f2bf(f2.w)<<16);
      r1.z = (u32)f2bf(f3.x) | ((u32)f2bf(f3.y)<<16);
      r1.w = (u32)f2bf(f3.z) | ((u32)f2bf(f3.w)<<16);
    }
    uint4* out = (uint4*)(eacsr + (size_t)p*16);
    out[0] = r0; out[1] = r1;
  }
}

// tile-advance (fallback k_msgmm only)
__device__ __forceinline__ void adv_tile(const int* __restrict__ rp,
                                         int ni, int bi, int ei,
                                         int& no, int& bo, int& eo){
  if (bi + 16 < ei){ no = ni; bo = bi + 16; eo = ei; return; }
  int t = ni + 1;
  int nb = ei;
  int ne = rp[(t < N_NODES) ? t + 1 : N_NODES];
  while (nb == ne && t + 1 < N_NODES){
    t++; nb = ne; ne = rp[t + 1];
  }
  no = t; bo = nb; eo = ne;
}

// ---------------- MFMA message kernel (old, fallback path) ----------------
__global__ void __launch_bounds__(256) k_msgmm(
    const u16* __restrict__ hsp, const void* __restrict__ ea,
    const int* __restrict__ rp, const int* __restrict__ perm2,
    const u16* __restrict__ Wl, u16* __restrict__ aggs,
    float* __restrict__ stats, const int* __restrict__ flagp,
    int nwaves){
  __shared__ float bs[128];
  int tid = threadIdx.x;
  if (tid < 128) bs[tid] = 0.f;
  __syncthreads();
  int isbf = *flagp;
  int lane = tid & 63, wv = tid >> 6;
  int w = blockIdx.x*4 + wv;
  long long t0 = (long long)w     * N_EDGES / nwaves;
  long long t1 = (long long)(w+1) * N_EDGES / nwaves;
  int lo = 0, hi = N_NODES;
  while (lo < hi){ int mid = (lo+hi)>>1; if ((long long)rp[mid] < t0) lo = mid+1; else hi = mid; }
  int n0 = lo, n1;
  if (w == nwaves-1) n1 = N_NODES;
  else {
    lo = 0; hi = N_NODES;
    while (lo < hi){ int mid = (lo+hi)>>1; if ((long long)rp[mid] < t1) lo = mid+1; else hi = mid; }
    n1 = lo;
  }
  int nn = lane & 15, kg = lane >> 4;
  bf16x8 B[3][4];
#pragma unroll
  for (int t = 0; t < 4; t++)
#pragma unroll
    for (int kb = 0; kb < 3; kb++)
      B[kb][t] = *(const bf16x8*)(Wl + (size_t)(t*16+nn)*96 + kb*32 + kg*8);
  U4BF ac; ac.u = make_uint4((kg==2)? 0x3f80u : 0u, 0u, 0u, 0u);
  float s1[4] = {0,0,0,0}, s2[4] = {0,0,0,0};
  for (int n = n0; n < n1; n++){
    int b0 = rp[n], b1 = rp[n+1];
    float r0 = 0.f, r1 = 0.f, r2 = 0.f, r3 = 0.f;
    for (int base = b0; base < b1; base += 16){
      int rem = b1 - base; if (rem > 16) rem = 16;
      int row = (nn < rem) ? nn : rem-1;
      int2 p = ((const int2*)perm2)[base + row];
      const uint4* hp = (const uint4*)(hsp + (size_t)p.x*128);
      U4BF fA, fB, fC;
      fA.u = hp[kg];
      fB.u = hp[4 + kg];
      if (kg < 2){
        if (isbf){
          fC.u = ((const uint4*)ea)[(size_t)p.y*2 + kg];
        } else {
          const float4* ef = (const float4*)ea;
          float4 f0 = ef[(size_t)p.y*4 + kg*2];
          float4 f1 = ef[(size_t)p.y*4 + kg*2 + 1];
          fC.u.x = (u32)f2bf(f0.x) | ((u32)f2bf(f0.y)<<16);
          fC.u.y = (u32)f2bf(f0.z) | ((u32)f2bf(f0.w)<<16);
          fC.u.z = (u32)f2bf(f1.x) | ((u32)f2bf(f1.y)<<16);
          fC.u.w = (u32)f2bf(f1.z) | ((u32)f2bf(f1.w)<<16);
        }
      } else fC = ac;
      f32x4 a0 = {0,0,0,0}, a1 = {0,0,0,0}, a2 = {0,0,0,0}, a3 = {0,0,0,0};
      a0 = __builtin_amdgcn_mfma_f32_16x16x32_bf16(fA.v, B[0][0], a0, 0,0,0);
      a1 = __builtin_amdgcn_mfma_f32_16x16x32_bf16(fA.v, B[0][1], a1, 0,0,0);
      a2 = __builtin_amdgcn_mfma_f32_16x16x32_bf16(fA.v, B[0][2], a2, 0,0,0);
      a3 = __builtin_amdgcn_mfma_f32_16x16x32_bf16(fA.v, B[0][3], a3, 0,0,0);
      a0 = __builtin_amdgcn_mfma_f32_16x16x32_bf16(fB.v, B[1][0], a0, 0,0,0);
      a1 = __builtin_amdgcn_mfma_f32_16x16x32_bf16(fB.v, B[1][1], a1, 0,0,0);
      a2 = __builtin_amdgcn_mfma_f32_16x16x32_bf16(fB.v, B[1][2], a2, 0,0,0);
      a3 = __builtin_amdgcn_mfma_f32_16x16x32_bf16(fB.v, B[1][3], a3, 0,0,0);
      a0 = __builtin_amdgcn_mfma_f32_16x16x32_bf16(fC.v, B[2][0], a0, 0,0,0);
      a1 = __builtin_amdgcn_mfma_f32_16x16x32_bf16(fC.v, B[2][1], a1, 0,0,0);
      a2 = __builtin_amdgcn_mfma_f32_16x16x32_bf16(fC.v, B[2][2], a2, 0,0,0);
      a3 = __builtin_amdgcn_mfma_f32_16x16x32_bf16(fC.v, B[2][3], a3, 0,0,0);
      int rowbase = kg*4;
      float ts0 = 0.f, ts1 = 0.f, ts2 = 0.f, ts3 = 0.f;
#pragma unroll
      for (int j = 0; j < 4; j++){
        bool valid = (rowbase + j) < rem;
        float m0 = fmaxf(a0[j], 0.f); m0 = valid ? m0 : 0.f;
        float m1 = fmaxf(a1[j], 0.f); m1 = valid ? m1 : 0.f;
        float m2 = fmaxf(a2[j], 0.f); m2 = valid ? m2 : 0.f;
        float m3 = fmaxf(a3[j], 0.f); m3 = valid ? m3 : 0.f;
        ts0 += m0; ts1 += m1; ts2 += m2; ts3 += m3;
        s2[0] = fmaf(m0,m0,s2[0]); s2[1] = fmaf(m1,m1,s2[1]);
        s2[2] = fmaf(m2,m2,s2[2]); s2[3] = fmaf(m3,m3,s2[3]);
      }
      s1[0] += ts0; s1[1] += ts1; s1[2] += ts2; s1[3] += ts3;
      ts0 += __shfl_xor(ts0,16); ts0 += __shfl_xor(ts0,32);
      ts1 += __shfl_xor(ts1,16); ts1 += __shfl_xor(ts1,32);
      ts2 += __shfl_xor(ts2,16); ts2 += __shfl_xor(ts2,32);
      ts3 += __shfl_xor(ts3,16); ts3 += __shfl_xor(ts3,32);
      r0 += ts0; r1 += ts1; r2 += ts2; r3 += ts3;
    }
    float v = (kg==0) ? r0 : (kg==1) ? r1 : (kg==2) ? r2 : r3;
    u16 hiv = f2bf(v);
    aggs[(size_t)n*128 + lane]      = hiv;
    aggs[(size_t)n*128 + 64 + lane] = f2bf(v - bf2f(hiv));
  }
#pragma unroll
  for (int t = 0; t < 4; t++){
    atomicAdd(&bs[t*16+nn], s1[t]);
    atomicAdd(&bs[64+t*16+nn], s2[t]);
  }
  __syncthreads();
  if (tid < 128) atomicAdd(&stats[tid], bs[tid]);
}

// ---------------- MFMA message kernel v3: flat tile-list walk ----------------
// Hot loop has ZERO rp traffic and no loop-carried scalar-load chain: tile
// records come from a dense per-wave list; base is a running sum of rem.
// Depth-2 operand prefetch as in v2; numerics identical (same tile order).
__global__ void __launch_bounds__(256) k_msgmm3(
    const u16* __restrict__ hsp, const u16* __restrict__ eacsr,
    const int* __restrict__ rp, const int* __restrict__ perm,
    const u16* __restrict__ Wl, u16* __restrict__ aggs,
    float* __restrict__ stats, const int* __restrict__ wranges,
    const int* __restrict__ twoff, const int* __restrict__ tlist){
  __shared__ float bs[128];
  int tid = threadIdx.x;
  if (tid < 128) bs[tid] = 0.f;
  __syncthreads();
  int lane = tid & 63;
  int w = blockIdx.x*4 + (tid >> 6);
  int nn = lane & 15, kg = lane >> 4;
  bf16x8 B[3][4];
#pragma unroll
  for (int t = 0; t < 4; t++)
#pragma unroll
    for (int kb = 0; kb < 3; kb++)
      B[kb][t] = *(const bf16x8*)(Wl + (size_t)(t*16+nn)*96 + kb*32 + kg*8);
  U4BF ac; ac.u = make_uint4((kg==2)? 0x3f80u : 0u, 0u, 0u, 0u);
  float s1[4] = {0,0,0,0}, s2[4] = {0,0,0,0};

  int nBeg = wranges[w], nEnd = wranges[w+1];
  // pre-pass: zero rows of empty nodes (rare; main walk skips them)
  if (nBeg < nEnd){
    int pv = rp[nBeg];
    for (int m = nBeg; m < nEnd; m++){
      int nx = rp[m+1];
      if (nx == pv){
        aggs[(size_t)m*128 + lane] = 0;
        aggs[(size_t)m*128 + 64 + lane] = 0;
      }
      pv = nx;
    }
  }

  int tB = twoff[w], tE = twoff[w+1];
  if (tB < tE){
    int recA = tlist[tB];
    int baseA = rp[nBeg];                 // first tile's base (empties share rp)
    int recB = (tB+1 < tE) ? tlist[tB+1] : recA;
    int baseB = baseA + ((recA>>1)&15) + 1;
    // prologue loads for tile A
    U4BF fAA, fAB, fAC;
    {
      int pA = perm[baseA + nn];
      const uint4* hpA = (const uint4*)(hsp + (size_t)pA*128);
      fAA.u = hpA[kg]; fAB.u = hpA[4 + kg];
      if (kg < 2) fAC.u = *(const uint4*)(eacsr + ((size_t)baseA + nn)*16 + (size_t)kg*8);
      else fAC = ac;
    }
    int pB = perm[baseB + nn];
    float r0 = 0.f, r1 = 0.f, r2 = 0.f, r3 = 0.f;
    for (int i = tB; i < tE; i++){
      // prefetch tile i+2's record/perm (clamped; values dead past tail)
      int recC = (i+2 < tE) ? tlist[i+2] : recB;
      int baseC = baseB + ((recB>>1)&15) + 1;
      int pC = perm[baseC + nn];
      // load tile i+1 operands (overlap with MFMA of tile i)
      const uint4* hpB = (const uint4*)(hsp + (size_t)pB*128);
      U4BF fBA, fBB, fBC;
      fBA.u = hpB[kg]; fBB.u = hpB[4 + kg];
      if (kg < 2) fBC.u = *(const uint4*)(eacsr + ((size_t)baseB + nn)*16 + (size_t)kg*8);
      else fBC = ac;
      // MFMA on tile i
      f32x4 a0 = {0,0,0,0}, a1 = {0,0,0,0}, a2 = {0,0,0,0}, a3 = {0,0,0,0};
      a0 = __builtin_amdgcn_mfma_f32_16x16x32_bf16(fAA.v, B[0][0], a0, 0,0,0);
      a1 = __builtin_amdgcn_mfma_f32_16x16x32_bf16(fAA.v, B[0][1], a1, 0,0,0);
      a2 = __builtin_amdgcn_mfma_f32_16x16x32_bf16(fAA.v, B[0][2], a2, 0,0,0);
      a3 = __builtin_amdgcn_mfma_f32_16x16x32_bf16(fAA.v, B[0][3], a3, 0,0,0);
      a0 = __builtin_amdgcn_mfma_f32_16x16x32_bf16(fAB.v, B[1][0], a0, 0,0,0);
      a1 = __builtin_amdgcn_mfma_f32_16x16x32_bf16(fAB.v, B[1][1], a1, 0,0,0);
      a2 = __builtin_amdgcn_mfma_f32_16x16x32_bf16(fAB.v, B[1][2], a2, 0,0,0);
      a3 = __builtin_amdgcn_mfma_f32_16x16x32_bf16(fAB.v, B[1][3], a3, 0,0,0);
      a0 = __builtin_amdgcn_mfma_f32_16x16x32_bf16(fAC.v, B[2][0], a0, 0,0,0);
      a1 = __builtin_amdgcn_mfma_f32_16x16x32_bf16(fAC.v, B[2][1], a1, 0,0,0);
      a2 = __builtin_amdgcn_mfma_f32_16x16x32_bf16(fAC.v, B[2][2], a2, 0,0,0);
      a3 = __builtin_amdgcn_mfma_f32_16x16x32_bf16(fAC.v, B[2][3], a3, 0,0,0);
      // epilogue for tile i
      int rem = ((recA >> 1) & 15) + 1;
      int rowbase = kg*4;
      float ts0 = 0.f, ts1 = 0.f, ts2 = 0.f, ts3 = 0.f;
#pragma unroll
      for (int j = 0; j < 4; j++){
        bool valid = (rowbase + j) < rem;
        float m0 = fmaxf(a0[j], 0.f); m0 = valid ? m0 : 0.f;
        float m1 = fmaxf(a1[j], 0.f); m1 = valid ? m1 : 0.f;
        float m2 = fmaxf(a2[j], 0.f); m2 = valid ? m2 : 0.f;
        float m3 = fmaxf(a3[j], 0.f); m3 = valid ? m3 : 0.f;
        ts0 += m0; ts1 += m1; ts2 += m2; ts3 += m3;
        s2[0] = fmaf(m0,m0,s2[0]); s2[1] = fmaf(m1,m1,s2[1]);
        s2[2] = fmaf(m2,m2,s2[2]); s2[3] = fmaf(m3,m3,s2[3]);
      }
      s1[0] += ts0; s1[1] += ts1; s1[2] += ts2; s1[3] += ts3;
      r0 += ts0; r1 += ts1; r2 += ts2; r3 += ts3;
      if (recA & 1){                      // last tile of its node
        r0 += __shfl_xor(r0,16); r0 += __shfl_xor(r0,32);
        r1 += __shfl_xor(r1,16); r1 += __shfl_xor(r1,32);
        r2 += __shfl_xor(r2,16); r2 += __shfl_xor(r2,32);
        r3 += __shfl_xor(r3,16); r3 += __shfl_xor(r3,32);
        float v = (kg==0) ? r0 : (kg==1) ? r1 : (kg==2) ? r2 : r3;
        int node = recA >> 5;
        u16 hiv = f2bf(v);
        aggs[(size_t)node*128 + lane]      = hiv;
        aggs[(size_t)node*128 + 64 + lane] = f2bf(v - bf2f(hiv));
        r0 = r1 = r2 = r3 = 0.f;
      }
      // rotate pipeline
      recA = recB; baseA = baseB;
      fAA = fBA; fAB = fBB; fAC = fBC;
      recB = recC; baseB = baseC; pB = pC;
    }
  }
#pragma unroll
  for (int t = 0; t < 4; t++){
    atomicAdd(&bs[t*16+nn], s1[t]);
    atomicAdd(&bs[64+t*16+nn], s2[t]);
  }
  __syncthreads();
  if (tid < 128) atomicAdd(&stats[tid], bs[tid]);
}

// ---------------- BN finalize (self-zeroes stats) ----------------
__global__ void k_fin(float* __restrict__ stats, const void* __restrict__ gamma,
                      const void* __restrict__ beta, float* __restrict__ aff,
                      float cnt_inv, int goff, const int* __restrict__ flagp){
  int isbf = *flagp; int c = threadIdx.x;
  float mu  = stats[c]      * cnt_inv;
  float var = stats[64 + c] * cnt_inv - mu*mu;
  float rs  = rsqrtf(var + 1e-5f);
  float g = ldf(gamma, (size_t)goff + c, isbf);
  float b = ldf(beta,  (size_t)goff + c, isbf);
  aff[c]      = g*rs;
  aff[64 + c] = b - g*mu*rs;
  stats[c] = 0.f; stats[64 + c] = 0.f;
}

// ---------------- MFMA fused update, split-precision ----------------
#define UPD_TILES (N_NODES/16)
__global__ void __launch_bounds__(256) k_updmm(
    const u16* __restrict__ hsp, u16* __restrict__ aggs,
    const float* __restrict__ degf, const u16* __restrict__ Wupd,
    const float* __restrict__ biasv, const float* __restrict__ tvv,
    float* __restrict__ stats){
  __shared__ float bs[128];
  int tid = threadIdx.x;
  if (tid < 128) bs[tid] = 0.f;
  __syncthreads();
  int lane = tid & 63;
  int nn = lane & 15, kg = lane >> 4;
  int w = blockIdx.x*4 + (tid >> 6);
  int nwv = gridDim.x*4;
  bf16x8 B[6][4];
#pragma unroll
  for (int t = 0; t < 4; t++)
#pragma unroll
    for (int kb = 0; kb < 6; kb++)
      B[kb][t] = *(const bf16x8*)(Wupd + (size_t)(t*16+nn)*192 + kb*32 + kg*8);
  float bc[4], tc[4];
#pragma unroll
  for (int t = 0; t < 4; t++){ bc[t] = biasv[t*16+nn]; tc[t] = tvv[t*16+nn]; }
  float s1[4] = {0,0,0,0}, s2[4] = {0,0,0,0};
  for (int tile = w; tile < UPD_TILES; tile += nwv){
    int n0 = tile*16;
    int r = n0 + nn;
    const uint4* hp = (const uint4*)hsp;
    const uint4* ap = (const uint4*)aggs;
    U4BF hh0, hh1, hl0, hl1, ah0, ah1, al0, al1;
    hh0.u = ntload4(&hp[(size_t)r*16 + kg]);       hh1.u = ntload4(&hp[(size_t)r*16 + 4 + kg]);
    hl0.u = ntload4(&hp[(size_t)r*16 + 8 + kg]);   hl1.u = ntload4(&hp[(size_t)r*16 + 12 + kg]);
    ah0.u = ntload4(&ap[(size_t)r*16 + kg]);       ah1.u = ntload4(&ap[(size_t)r*16 + 4 + kg]);
    al0.u = ntload4(&ap[(size_t)r*16 + 8 + kg]);   al1.u = ntload4(&ap[(size_t)r*16 + 12 + kg]);
    float dg[4];
#pragma unroll
    for (int j = 0; j < 4; j++) dg[j] = degf[n0 + kg*4 + j];
    f32x4 a0 = {0,0,0,0}, a1 = {0,0,0,0}, a2 = {0,0,0,0}, a3 = {0,0,0,0};
#define MF(F,KB) \
    a0 = __builtin_amdgcn_mfma_f32_16x16x32_bf16(F.v, B[KB][0], a0, 0,0,0); \
    a1 = __builtin_amdgcn_mfma_f32_16x16x32_bf16(F.v, B[KB][1], a1, 0,0,0); \
    a2 = __builtin_amdgcn_mfma_f32_16x16x32_bf16(F.v, B[KB][2], a2, 0,0,0); \
    a3 = __builtin_amdgcn_mfma_f32_16x16x32_bf16(F.v, B[KB][3], a3, 0,0,0);
    MF(hh0,0) MF(hh1,1) MF(hl0,0) MF(hl1,1)
    MF(ah0,2) MF(ah1,3) MF(ah0,4) MF(ah1,5)
    MF(al0,2) MF(al1,3)
#undef MF
#pragma unroll
    for (int j = 0; j < 4; j++){
      int n = n0 + kg*4 + j;
      float m0 = fmaxf(fmaf(tc[0], dg[j], a0[j] + bc[0]), 0.f);
      float m1 = fmaxf(fmaf(tc[1], dg[j], a1[j] + bc[1]), 0.f);
      float m2 = fmaxf(fmaf(tc[2], dg[j], a2[j] + bc[2]), 0.f);
      float m3 = fmaxf(fmaf(tc[3], dg[j], a3[j] + bc[3]), 0.f);
      s1[0] += m0; s1[1] += m1; s1[2] += m2; s1[3] += m3;
      s2[0] = fmaf(m0,m0,s2[0]); s2[1] = fmaf(m1,m1,s2[1]);
      s2[2] = fmaf(m2,m2,s2[2]); s2[3] = fmaf(m3,m3,s2[3]);
      u16* hw = aggs + (size_t)n*128;
      u16 q0 = f2bf(m0), q1 = f2bf(m1), q2 = f2bf(m2), q3 = f2bf(m3);
      hw[     nn] = q0;  hw[64 +      nn] = f2bf(m0 - bf2f(q0));
      hw[16 + nn] = q1;  hw[64 + 16 + nn] = f2bf(m1 - bf2f(q1));
      hw[32 + nn] = q2;  hw[64 + 32 + nn] = f2bf(m2 - bf2f(q2));
      hw[48 + nn] = q3;  hw[64 + 48 + nn] = f2bf(m3 - bf2f(q3));
    }
  }
#pragma unroll
  for (int t = 0; t < 4; t++){
    atomicAdd(&bs[t*16+nn], s1[t]);
    atomicAdd(&bs[64+t*16+nn], s2[t]);
  }
  __syncthreads();
  if (tid < 128) atomicAdd(&stats[tid], bs[tid]);
}

// ---------------- global add pool over PRE-BN h with affine applied ----------
__global__ void k_pool(const u16* __restrict__ hsp, const int* __restrict__ batch,
                       const float* __restrict__ aff, float* __restrict__ g){
  int lane = threadIdx.x & 63;
  int gw = (blockIdx.x*blockDim.x + threadIdx.x) >> 6;
  int nw = (gridDim.x*blockDim.x) >> 6;
  float s = aff[lane], t = aff[64 + lane];
  int chunk = (N_NODES + nw - 1) / nw;
  int n0 = gw*chunk;
  int n1 = n0 + chunk; if (n1 > N_NODES) n1 = N_NODES;
  int cur = -1; float acc = 0.f, cnt = 0.f;
  for (int n = n0; n < n1; n++){
    int b = batch[n];
    float v = bf2f(hsp[(size_t)n*128 + lane]) + bf2f(hsp[(size_t)n*128 + 64 + lane]);
    if (b != cur){
      if (cur >= 0) atomicAdd(&g[(size_t)cur*64 + lane], fmaf(s, acc, t*cnt));
      cur = b; acc = v; cnt = 1.f;
    } else { acc += v; cnt += 1.f; }
  }
  if (cur >= 0) atomicAdd(&g[(size_t)cur*64 + lane], fmaf(s, acc, t*cnt));
}

// ---------------- readout ----------------
__global__ void k_read(const float* __restrict__ g, const void* __restrict__ r1W,
                       const void* __restrict__ r1b, const void* __restrict__ r2W,
                       const void* __restrict__ r2b, void* __restrict__ out,
                       const int* __restrict__ flagp){
  int isbf = *flagp;
  int lane = threadIdx.x;
  int gr = blockIdx.x;
  float w[64];
#pragma unroll
  for (int k = 0; k < 64; k++) w[k] = ldf(r1W, (size_t)k*64 + lane, isbf);
  float acc = ldf(r1b, lane, isbf);
  const float4* grow = (const float4*)(g + (size_t)gr*64);
#pragma unroll
  for (int q = 0; q < 16; q++){
    float4 a = grow[q];
    acc = fmaf(a.x, w[4*q+0], acc); acc = fmaf(a.y, w[4*q+1], acc);
    acc = fmaf(a.z, w[4*q+2], acc); acc = fmaf(a.w, w[4*q+3], acc);
  }
  float hid = fmaxf(acc, 0.f);
  float p = hid * ldf(r2W, lane, isbf);
  for (int o = 32; o; o >>= 1) p += __shfl_xor(p, o);
  if (lane == 0){
    float v = p + ldf(r2b, 0, isbf);
    if (isbf) ((__hip_bfloat16*)out)[gr] = __float2bfloat16(v);
    else      ((float*)out)[gr] = v;
  }
}

extern "C" void kernel_launch(void* const* d_in, const int* in_sizes, int n_in,
                              void* d_out, int out_size, void* d_ws, size_t ws_size,
                              hipStream_t stream){
  const void* x    = d_in[0];
  const void* ea   = d_in[1];
  const int*  ei   = (const int*)d_in[2];
  const int*  bt   = (const int*)d_in[3];
  const void* nW   = d_in[4];  const void* nb  = d_in[5];
  const void* eW   = d_in[6];  const void* eb  = d_in[7];
  const void* mW   = d_in[8];  const void* mb  = d_in[9];
  const void* mg   = d_in[10]; const void* mbe = d_in[11];
  const void* uW   = d_in[12]; const void* ub  = d_in[13];
  const void* ug   = d_in[14]; const void* ube = d_in[15];
  const void* r1W  = d_in[16]; const void* r1b = d_in[17];
  const void* r2W  = d_in[18]; const void* r2b = d_in[19];

  // big path needs 27,908,684 floats = 111,634,736 bytes
  const size_t NEED_BIG = 111634736ull;
  const bool big = (ws_size >= NEED_BIG);

  float* ws = (float*)d_ws;
  size_t off = 0;
  auto alloc = [&](size_t n){ float* p = ws + off; off += n; return p; };

  u16*   hsp   = (u16*)alloc(6400000);
  u16*   aggs  = (u16*)alloc(6400000);
  u16*   eacsr = nullptr; int* perm = nullptr; int* perm2 = nullptr;
  int*   tcnt = nullptr; int* twoff = nullptr; int* tlist = nullptr;
  if (big){
    eacsr = (u16*)alloc(12800384);          // (E+48) rows x 16 u16
    perm  = (int*)alloc(1600048);           // E+48 ints
  } else {
    perm2 = (int*)alloc(3200000);           // E int2
  }
  float* degf   = alloc(100000);
  float* zero0  = ws + off;                 // memset region start
  int*   deg_i  = (int*)alloc(100000);
  float* g      = alloc(64000);
  float* mstats = alloc(128);
  float* ustats = alloc(128);
  size_t zeroN  = (size_t)((ws + off) - zero0);   // 164,256 floats
  float* maff   = alloc(128);
  float* haff   = alloc(128);
  int*   flag   = (int*)alloc(16);
  u16*   Weff   = (u16*)alloc(9216);        // base msg weights (3 layers)
  u16*   Wfold  = (u16*)alloc(3072);        // per-layer folded msg weights
  u16*   Wupd   = (u16*)alloc(6144);
  float* biasm  = alloc(192);               // f32 base msg bias (3 layers)
  float* biasv  = alloc(64);
  float* tvv    = alloc(64);
  int*   row_ptr= (int*)alloc(100001);
  int*   cursor = (int*)alloc(100000);
  int*   bsum   = (int*)alloc(196);
  int*   boff   = (int*)alloc(196);
  int*   wrng   = (int*)alloc(8194);        // wave ranges (MM_WAVES+1)
  if (big){
    tcnt  = (int*)alloc(8192);
    twoff = (int*)alloc(8193);
    tlist = (int*)alloc(200000);            // <= E/16 + N tiles
  }

  const int MM_BLOCKS = 2048;
  const int MM_WAVES  = MM_BLOCKS * 4;
  const int UPD_BLOCKS = 782;

  k_detect<<<1, 64, 0, stream>>>((const u32*)x, flag);
  hipMemsetAsync(zero0, 0, zeroN*sizeof(float), stream);
  k_idaff<<<1, 64, 0, stream>>>(haff);
  k_prep<<<3, 64, 0, stream>>>(eW, eb, mW, mb, Weff, biasm, flag);
  k_node_emb<<<256, 256, 0, stream>>>(x, nW, nb, hsp, flag);
  k_deg<<<512, 256, 0, stream>>>(ei, deg_i);
  k_scan1<<<196, 256, 0, stream>>>(deg_i, bsum);
  k_scan2<<<1, 256, 0, stream>>>(bsum, boff, row_ptr);
  k_scan3<<<196, 256, 0, stream>>>(deg_i, boff, row_ptr, cursor, degf);
  if (big){
    k_ranges<<<33, 256, 0, stream>>>(row_ptr, wrng, MM_WAVES);
    k_tcnt<<<32, 256, 0, stream>>>(row_ptr, wrng, tcnt, MM_WAVES);
    k_tscan<<<1, 256, 0, stream>>>(tcnt, twoff, MM_WAVES);
    k_tfill<<<32, 256, 0, stream>>>(row_ptr, wrng, twoff, tlist, MM_WAVES);
    k_scatter2<<<512, 256, 0, stream>>>(ei, cursor, perm, eacsr, ea, flag);
  } else {
    k_scatter<<<512, 256, 0, stream>>>(ei, cursor, perm2);
  }

  u16* H = hsp;   // current h (layer 0: embedding; l>0: pre-BN relu(u), haff pending)
  u16* G = aggs;  // scratch: msg agg, then overwritten by pre-BN relu(u)
  for (int l = 0; l < 3; l++){
    k_fold<<<1, 64, 0, stream>>>(mW, Weff, biasm, haff, Wfold, flag, l);
    if (big)
      k_msgmm3<<<MM_BLOCKS, 256, 0, stream>>>(H, eacsr, row_ptr, perm, Wfold,
                                              G, mstats, wrng, twoff, tlist);
    else
      k_msgmm<<<MM_BLOCKS, 256, 0, stream>>>(H, ea, row_ptr, perm2, Wfold,
                                             G, mstats, flag, MM_WAVES);
    k_fin<<<1, 64, 0, stream>>>(mstats, mg, mbe, maff, 1.0f/(float)N_EDGES, l*64, flag);
    k_updprep<<<1, 64, 0, stream>>>(uW, ub, maff, haff, Wupd, biasv, tvv, flag, l);
    k_updmm<<<UPD_BLOCKS, 256, 0, stream>>>(H, G, degf, Wupd, biasv, tvv, ustats);
    k_fin<<<1, 64, 0, stream>>>(ustats, ug, ube, haff, 1.0f/(float)N_NODES, l*64, flag);
    u16* tmp = H; H = G; G = tmp;
  }

  k_pool<<<128, 256, 0, stream>>>(H, bt, haff, g);
  k_read<<<NUM_GRAPHS, 64, 0, stream>>>(g, r1W, r1b, r2W, r2b, d_out, flag);
}

// Round 15
// 1310.044 us; speedup vs baseline: 1.0785x; 1.0067x over previous
//
#include <hip/hip_runtime.h>
#include <hip/hip_bf16.h>

#define N_NODES   100000
#define N_EDGES   1600000
#define NUM_GRAPHS 1000

typedef unsigned int u32;
typedef unsigned short u16;

typedef __bf16 bf16_t;
typedef bf16_t bf16x8 __attribute__((ext_vector_type(8)));
typedef float  f32x4  __attribute__((ext_vector_type(4)));
typedef u32    u32x4  __attribute__((ext_vector_type(4)));

__device__ __forceinline__ float bf2f(u16 u){ return __uint_as_float(((u32)u)<<16); }
__device__ __forceinline__ float BL(u32 u){ return __uint_as_float(u<<16); }
__device__ __forceinline__ float BH(u32 u){ return __uint_as_float(u&0xffff0000u); }
// f32 -> bf16 bits, round-to-nearest-even
__device__ __forceinline__ u16 f2bf(float f){
  u32 u = __float_as_uint(f);
  return (u16)((u + 0x7fffu + ((u>>16)&1u)) >> 16);
}
// dual-dtype scalar load: isbf=1 -> bf16, else f32
__device__ __forceinline__ float ldf(const void* p, size_t i, int isbf){
  return isbf ? bf2f(((const u16*)p)[i]) : ((const float*)p)[i];
}
// NT history: r8 NT stores on random scatter = 3x write amp (removed).
// r12: NT loads on msgmm streams RAISED FETCH 121.7->130MB (L3 bypass; removed).
// r15: NT loads in updmm read L3-RESIDENT data (hsp/aggs freshly written) ->
// forced HBM re-fetch + cold L3 for next msgmm.  All NT hints now removed.

union U4BF { uint4 u; bf16x8 v; };

// ---------------- dtype detector ----------------
__global__ void k_detect(const u32* __restrict__ x, int* __restrict__ flag){
  int t = threadIdx.x; int cnt = 0;
  for (int i = t; i < 256; i += 64){
    u32 w = x[i];
    u32 e = (w >> 7) & 0xffu;
    if (e >= 110u && e <= 137u) cnt++;
  }
  for (int o = 32; o; o >>= 1) cnt += __shfl_xor(cnt, o);
  if (t == 0) *flag = (cnt > 128) ? 1 : 0;
}

// ---------------- identity affine init: s=1, t=0 ----------------
__global__ void k_idaff(float* __restrict__ haff){
  int c = threadIdx.x;
  haff[c] = 1.f; haff[64 + c] = 0.f;
}

// ---------------- weight prep: base Weff[l][c][96] + f32 base bias ---------
__global__ void k_prep(const void* __restrict__ eW, const void* __restrict__ eb,
                       const void* __restrict__ mW, const void* __restrict__ mb,
                       u16* __restrict__ Weff, float* __restrict__ biasm,
                       const int* __restrict__ flagp){
  int isbf = *flagp;
  int l = blockIdx.x, c = threadIdx.x;
  u16* W = Weff + ((size_t)l*64 + c)*96;
  for (int k = 0; k < 64; k++)
    W[k] = f2bf(ldf(mW, (size_t)(l*96 + k)*64 + c, isbf));
  for (int j = 0; j < 16; j++){
    float acc = 0.f;
    for (int k = 0; k < 32; k++)
      acc += ldf(eW, (size_t)j*32 + k, isbf) * ldf(mW, (size_t)(l*96 + 64 + k)*64 + c, isbf);
    W[64 + j] = f2bf(acc);
  }
  float fbv = ldf(mb, (size_t)l*64 + c, isbf);
  for (int k = 0; k < 32; k++)
    fbv += ldf(eb, k, isbf) * ldf(mW, (size_t)(l*96 + 64 + k)*64 + c, isbf);
  W[80] = f2bf(fbv);
  biasm[(size_t)l*64 + c] = fbv;
  for (int k = 81; k < 96; k++) W[k] = 0;
}

// ---------------- per-layer msg-weight fold ----------------
__global__ void k_fold(const void* __restrict__ mW, const u16* __restrict__ Wbase,
                       const float* __restrict__ biasm, const float* __restrict__ haff,
                       u16* __restrict__ Wf, const int* __restrict__ flagp, int l){
  int isbf = *flagp; int c = threadIdx.x;
  const u16* Wb = Wbase + ((size_t)l*64 + c)*96;
  u16* W = Wf + (size_t)c*96;
  float bb = biasm[(size_t)l*64 + c];
  for (int k = 0; k < 64; k++){
    float w = ldf(mW, (size_t)(l*96 + k)*64 + c, isbf);
    W[k] = f2bf(haff[k] * w);
    bb = fmaf(haff[64 + k], w, bb);
  }
  for (int k = 64; k < 80; k++) W[k] = Wb[k];
  W[80] = f2bf(bb);
  for (int k = 81; k < 96; k++) W[k] = 0;
}

// ---------------- update-weight prep ----------------
__global__ void k_updprep(const void* __restrict__ uW, const void* __restrict__ ub,
                          const float* __restrict__ maff, const float* __restrict__ haff,
                          u16* __restrict__ Wupd, float* __restrict__ biasv,
                          float* __restrict__ tvv, const int* __restrict__ flagp, int l){
  int isbf = *flagp; int c = threadIdx.x;
  u16* W = Wupd + (size_t)c*192;
  float tv = 0.f, bb = 0.f;
  for (int k = 0; k < 64; k++){
    float wka = ldf(uW, (size_t)(l*128 + k)*64 + c, isbf);
    W[k] = f2bf(haff[k] * wka);
    bb = fmaf(haff[64 + k], wka, bb);
    float wkb = ldf(uW, (size_t)(l*128 + 64 + k)*64 + c, isbf);
    float prod = wkb * maff[k];
    u16 hi = f2bf(prod);
    W[64 + k]  = hi;
    W[128 + k] = f2bf(prod - bf2f(hi));
    tv = fmaf(maff[64 + k], wkb, tv);
  }
  biasv[c] = ldf(ub, (size_t)l*64 + c, isbf) + bb;
  tvv[c] = tv;
}

// ---------------- node embedding -> hsp split hi/lo ----
__global__ void k_node_emb(const void* __restrict__ x, const void* __restrict__ nW,
                           const void* __restrict__ nb, u16* __restrict__ hsp,
                           const int* __restrict__ flagp){
  int isbf = *flagp;
  int lane = threadIdx.x & 63;
  int gw = (blockIdx.x*blockDim.x + threadIdx.x) >> 6;
  int nw = (gridDim.x*blockDim.x) >> 6;
  float w[32];
#pragma unroll
  for (int k = 0; k < 32; k++) w[k] = ldf(nW, (size_t)k*64 + lane, isbf);
  float bias = ldf(nb, lane, isbf);
  for (int n = gw; n < N_NODES; n += nw){
    float acc = bias;
    if (isbf){
      const uint4* xr = (const uint4*)((const u16*)x + (size_t)n*32);
#pragma unroll
      for (int q = 0; q < 4; q++){
        uint4 a = xr[q];
        u32 uu[4] = {a.x, a.y, a.z, a.w};
#pragma unroll
        for (int j = 0; j < 4; j++){
          acc = fmaf(BL(uu[j]), w[q*8 + 2*j + 0], acc);
          acc = fmaf(BH(uu[j]), w[q*8 + 2*j + 1], acc);
        }
      }
    } else {
      const float4* xr = (const float4*)((const float*)x + (size_t)n*32);
#pragma unroll
      for (int q = 0; q < 8; q++){
        float4 a = xr[q];
        acc = fmaf(a.x, w[q*4+0], acc); acc = fmaf(a.y, w[q*4+1], acc);
        acc = fmaf(a.z, w[q*4+2], acc); acc = fmaf(a.w, w[q*4+3], acc);
      }
    }
    u16 hi = f2bf(acc);
    hsp[(size_t)n*128 + lane]      = hi;
    hsp[(size_t)n*128 + 64 + lane] = f2bf(acc - bf2f(hi));
  }
}

// ---------------- in-degree histogram ----------------
__global__ void k_deg(const int* __restrict__ ei, int* __restrict__ deg){
  int i = blockIdx.x*blockDim.x + threadIdx.x;
  int stride = gridDim.x*blockDim.x;
  for (int e = i; e < N_EDGES; e += stride)
    atomicAdd(&deg[ei[N_EDGES + e]], 1);
}

// ---------------- multi-block scan: phase 1 ----------------
__global__ void __launch_bounds__(256) k_scan1(const int* __restrict__ deg,
                                               int* __restrict__ bsum){
  __shared__ int wsum[4];
  int b = blockIdx.x, t = threadIdx.x;
  int i0 = b*512 + t;
  int s = 0;
  if (i0 < N_NODES) s += deg[i0];
  if (i0 + 256 < N_NODES) s += deg[i0 + 256];
  for (int o = 32; o; o >>= 1) s += __shfl_xor(s, o);
  if ((t & 63) == 0) wsum[t >> 6] = s;
  __syncthreads();
  if (t == 0) bsum[b] = wsum[0] + wsum[1] + wsum[2] + wsum[3];
}

// ---------------- scan phase 2 ----------------
__global__ void k_scan2(const int* __restrict__ bsum, int* __restrict__ boff,
                        int* __restrict__ rp){
  __shared__ int l[200];
  int t = threadIdx.x;
  if (t < 196) l[t] = bsum[t];
  __syncthreads();
  if (t == 0){
    int r = 0;
    for (int k = 0; k < 196; k++){ int x = l[k]; l[k] = r; r += x; }
    rp[N_NODES] = r;
  }
  __syncthreads();
  if (t < 196) boff[t] = l[t];
}

// ---------------- scan phase 3 ----------------
__global__ void __launch_bounds__(256) k_scan3(const int* __restrict__ deg,
                        const int* __restrict__ boff, int* __restrict__ rp,
                        int* __restrict__ cursor, float* __restrict__ degf){
  __shared__ int wpre[4];
  int b = blockIdx.x, t = threadIdx.x;
  int i0 = b*512 + 2*t;
  int d0 = (i0     < N_NODES) ? deg[i0]     : 0;
  int d1 = (i0 + 1 < N_NODES) ? deg[i0 + 1] : 0;
  int s = d0 + d1;
  int incl = s;
  for (int o = 1; o < 64; o <<= 1){ int u = __shfl_up(incl, o); if ((t & 63) >= o) incl += u; }
  if ((t & 63) == 63) wpre[t >> 6] = incl;
  __syncthreads();
  if (t == 0){ int r = 0; for (int k = 0; k < 4; k++){ int x = wpre[k]; wpre[k] = r; r += x; } }
  __syncthreads();
  int excl = boff[b] + wpre[t >> 6] + incl - s;
  if (i0 < N_NODES){
    rp[i0] = excl; cursor[i0] = excl; degf[i0] = (float)d0;
  }
  if (i0 + 1 < N_NODES){
    rp[i0+1] = excl + d0; cursor[i0+1] = excl + d0; degf[i0+1] = (float)d1;
  }
}

// ---------------- wave ranges: wr[w] = first node with rp >= w*E/nw -------
__global__ void k_ranges(const int* __restrict__ rp, int* __restrict__ wr,
                         int nwaves){
  int w = blockIdx.x*blockDim.x + threadIdx.x;
  if (w > nwaves) return;
  if (w == nwaves){ wr[w] = N_NODES; return; }
  long long t0 = (long long)w * N_EDGES / nwaves;
  int lo = 0, hi = N_NODES;
  while (lo < hi){ int mid = (lo+hi)>>1; if ((long long)rp[mid] < t0) lo = mid+1; else hi = mid; }
  wr[w] = lo;
}

// ---------------- flat tile list (r13): removes the serial rp-walk from the
// msgmm hot loop.  record = node<<5 | (rem-1)<<1 | last  (4B/tile; base is a
// running sum of rem starting at rp[wr[w]]).

// per-wave tile count
__global__ void k_tcnt(const int* __restrict__ rp, const int* __restrict__ wr,
                       int* __restrict__ tcnt, int nwaves){
  int w = blockIdx.x*blockDim.x + threadIdx.x;
  if (w >= nwaves) return;
  int n0 = wr[w], n1 = wr[w+1];
  int c = 0;
  for (int n = n0; n < n1; n++){
    int d = rp[n+1] - rp[n];
    c += (d + 15) >> 4;
  }
  tcnt[w] = c;
}

// exclusive scan of nwaves (=8192 = 256*32) counts -> twoff[0..nwaves]
__global__ void k_tscan(const int* __restrict__ tcnt, int* __restrict__ twoff,
                        int nwaves){
  __shared__ int ps[256];
  int t = threadIdx.x;
  int s = 0;
  for (int i = 0; i < 32; i++) s += tcnt[t*32 + i];
  ps[t] = s;
  __syncthreads();
  if (t == 0){
    int r = 0;
    for (int k = 0; k < 256; k++){ int x = ps[k]; ps[k] = r; r += x; }
    twoff[nwaves] = r;
  }
  __syncthreads();
  int off = ps[t];
  for (int i = 0; i < 32; i++){
    twoff[t*32 + i] = off;
    off += tcnt[t*32 + i];
  }
}

// fill tile records
__global__ void k_tfill(const int* __restrict__ rp, const int* __restrict__ wr,
                        const int* __restrict__ twoff, int* __restrict__ tlist,
                        int nwaves){
  int w = blockIdx.x*blockDim.x + threadIdx.x;
  if (w >= nwaves) return;
  int n0 = wr[w], n1 = wr[w+1];
  int o = twoff[w];
  for (int n = n0; n < n1; n++){
    int b = rp[n], e = rp[n+1];
    while (b < e){
      int rem = e - b; if (rem > 16) rem = 16;
      int last = (b + 16 >= e) ? 1 : 0;
      tlist[o++] = (n << 5) | ((rem - 1) << 1) | last;
      b += 16;
    }
  }
}

// ---------------- CSR scatter (fallback path: int2 perm2) ----------------
__global__ void k_scatter(const int* __restrict__ ei, int* __restrict__ cursor,
                          int* __restrict__ perm2){
  int i = blockIdx.x*blockDim.x + threadIdx.x;
  int stride = gridDim.x*blockDim.x;
  for (int e = i; e < N_EDGES; e += stride){
    int d = ei[N_EDGES + e];
    int p = atomicAdd(&cursor[d], 1);
    ((int2*)perm2)[p] = make_int2(ei[e], e);
  }
}

// ---------------- CSR scatter v2: perm (src only) + edge attrs permuted to
// CSR order as bf16.  REGULAR stores (r8: NT stores = 3x write amp).
// Pads 48 slots past E (covers depth-2 base lookahead of up to +32). ----
__global__ void k_scatter2(const int* __restrict__ ei, int* __restrict__ cursor,
                           int* __restrict__ perm, u16* __restrict__ eacsr,
                           const void* __restrict__ ea, const int* __restrict__ flagp){
  int isbf = *flagp;
  int i = blockIdx.x*blockDim.x + threadIdx.x;
  int stride = gridDim.x*blockDim.x;
  if (i < 48){
    perm[N_EDGES + i] = 0;
    uint4 z = make_uint4(0,0,0,0);
    uint4* out = (uint4*)(eacsr + (size_t)(N_EDGES + i)*16);
    out[0] = z; out[1] = z;
  }
  for (int e = i; e < N_EDGES; e += stride){
    int d = ei[N_EDGES + e];
    int p = atomicAdd(&cursor[d], 1);
    perm[p] = ei[e];
    uint4 r0, r1;
    if (isbf){
      const uint4* er = (const uint4*)((const u16*)ea + (size_t)e*16);
      r0 = er[0]; r1 = er[1];
    } else {
      const float4* ef = (const float4*)((const float*)ea + (size_t)e*16);
      float4 f0 = ef[0], f1 = ef[1], f2 = ef[2], f3 = ef[3];
      r0.x = (u32)f2bf(f0.x) | ((u32)f2bf(f0.y)<<16);
      r0.y = (u32)f2bf(f0.z) | ((u32)f2bf(f0.w)<<16);
      r0.z = (u32)f2bf(f1.x) | ((u32)f2bf(f1.y)<<16);
      r0.w = (u32)f2bf(f1.z) | ((u32)f2bf(f1.w)<<16);
      r1.x = (u32)f2bf(f2.x) | ((u32)f2bf(f2.y)<<16);
      r1.y = (u32)f2bf(f2.z) | ((u32)f2bf(f2.w)<<16);
      r1.z = (u32)f2bf(f3.x) | ((u32)f2bf(f3.y)<<16);
      r1.w = (u32)f2bf(f3.z) | ((u32)f2bf(f3.w)<<16);
    }
    uint4* out = (uint4*)(eacsr + (size_t)p*16);
    out[0] = r0; out[1] = r1;
  }
}

// tile-advance (fallback k_msgmm only)
__device__ __forceinline__ void adv_tile(const int* __restrict__ rp,
                                         int ni, int bi, int ei,
                                         int& no, int& bo, int& eo){
  if (bi + 16 < ei){ no = ni; bo = bi + 16; eo = ei; return; }
  int t = ni + 1;
  int nb = ei;
  int ne = rp[(t < N_NODES) ? t + 1 : N_NODES];
  while (nb == ne && t + 1 < N_NODES){
    t++; nb = ne; ne = rp[t + 1];
  }
  no = t; bo = nb; eo = ne;
}

// ---------------- MFMA message kernel (old, fallback path) ----------------
__global__ void __launch_bounds__(256) k_msgmm(
    const u16* __restrict__ hsp, const void* __restrict__ ea,
    const int* __restrict__ rp, const int* __restrict__ perm2,
    const u16* __restrict__ Wl, u16* __restrict__ aggs,
    float* __restrict__ stats, const int* __restrict__ flagp,
    int nwaves){
  __shared__ float bs[128];
  int tid = threadIdx.x;
  if (tid < 128) bs[tid] = 0.f;
  __syncthreads();
  int isbf = *flagp;
  int lane = tid & 63, wv = tid >> 6;
  int w = blockIdx.x*4 + wv;
  long long t0 = (long long)w     * N_EDGES / nwaves;
  long long t1 = (long long)(w+1) * N_EDGES / nwaves;
  int lo = 0, hi = N_NODES;
  while (lo < hi){ int mid = (lo+hi)>>1; if ((long long)rp[mid] < t0) lo = mid+1; else hi = mid; }
  int n0 = lo, n1;
  if (w == nwaves-1) n1 = N_NODES;
  else {
    lo = 0; hi = N_NODES;
    while (lo < hi){ int mid = (lo+hi)>>1; if ((long long)rp[mid] < t1) lo = mid+1; else hi = mid; }
    n1 = lo;
  }
  int nn = lane & 15, kg = lane >> 4;
  bf16x8 B[3][4];
#pragma unroll
  for (int t = 0; t < 4; t++)
#pragma unroll
    for (int kb = 0; kb < 3; kb++)
      B[kb][t] = *(const bf16x8*)(Wl + (size_t)(t*16+nn)*96 + kb*32 + kg*8);
  U4BF ac; ac.u = make_uint4((kg==2)? 0x3f80u : 0u, 0u, 0u, 0u);
  float s1[4] = {0,0,0,0}, s2[4] = {0,0,0,0};
  for (int n = n0; n < n1; n++){
    int b0 = rp[n], b1 = rp[n+1];
    float r0 = 0.f, r1 = 0.f, r2 = 0.f, r3 = 0.f;
    for (int base = b0; base < b1; base += 16){
      int rem = b1 - base; if (rem > 16) rem = 16;
      int row = (nn < rem) ? nn : rem-1;
      int2 p = ((const int2*)perm2)[base + row];
      const uint4* hp = (const uint4*)(hsp + (size_t)p.x*128);
      U4BF fA, fB, fC;
      fA.u = hp[kg];
      fB.u = hp[4 + kg];
      if (kg < 2){
        if (isbf){
          fC.u = ((const uint4*)ea)[(size_t)p.y*2 + kg];
        } else {
          const float4* ef = (const float4*)ea;
          float4 f0 = ef[(size_t)p.y*4 + kg*2];
          float4 f1 = ef[(size_t)p.y*4 + kg*2 + 1];
          fC.u.x = (u32)f2bf(f0.x) | ((u32)f2bf(f0.y)<<16);
          fC.u.y = (u32)f2bf(f0.z) | ((u32)f2bf(f0.w)<<16);
          fC.u.z = (u32)f2bf(f1.x) | ((u32)f2bf(f1.y)<<16);
          fC.u.w = (u32)f2bf(f1.z) | ((u32)f2bf(f1.w)<<16);
        }
      } else fC = ac;
      f32x4 a0 = {0,0,0,0}, a1 = {0,0,0,0}, a2 = {0,0,0,0}, a3 = {0,0,0,0};
      a0 = __builtin_amdgcn_mfma_f32_16x16x32_bf16(fA.v, B[0][0], a0, 0,0,0);
      a1 = __builtin_amdgcn_mfma_f32_16x16x32_bf16(fA.v, B[0][1], a1, 0,0,0);
      a2 = __builtin_amdgcn_mfma_f32_16x16x32_bf16(fA.v, B[0][2], a2, 0,0,0);
      a3 = __builtin_amdgcn_mfma_f32_16x16x32_bf16(fA.v, B[0][3], a3, 0,0,0);
      a0 = __builtin_amdgcn_mfma_f32_16x16x32_bf16(fB.v, B[1][0], a0, 0,0,0);
      a1 = __builtin_amdgcn_mfma_f32_16x16x32_bf16(fB.v, B[1][1], a1, 0,0,0);
      a2 = __builtin_amdgcn_mfma_f32_16x16x32_bf16(fB.v, B[1][2], a2, 0,0,0);
      a3 = __builtin_amdgcn_mfma_f32_16x16x32_bf16(fB.v, B[1][3], a3, 0,0,0);
      a0 = __builtin_amdgcn_mfma_f32_16x16x32_bf16(fC.v, B[2][0], a0, 0,0,0);
      a1 = __builtin_amdgcn_mfma_f32_16x16x32_bf16(fC.v, B[2][1], a1, 0,0,0);
      a2 = __builtin_amdgcn_mfma_f32_16x16x32_bf16(fC.v, B[2][2], a2, 0,0,0);
      a3 = __builtin_amdgcn_mfma_f32_16x16x32_bf16(fC.v, B[2][3], a3, 0,0,0);
      int rowbase = kg*4;
      float ts0 = 0.f, ts1 = 0.f, ts2 = 0.f, ts3 = 0.f;
#pragma unroll
      for (int j = 0; j < 4; j++){
        bool valid = (rowbase + j) < rem;
        float m0 = fmaxf(a0[j], 0.f); m0 = valid ? m0 : 0.f;
        float m1 = fmaxf(a1[j], 0.f); m1 = valid ? m1 : 0.f;
        float m2 = fmaxf(a2[j], 0.f); m2 = valid ? m2 : 0.f;
        float m3 = fmaxf(a3[j], 0.f); m3 = valid ? m3 : 0.f;
        ts0 += m0; ts1 += m1; ts2 += m2; ts3 += m3;
        s2[0] = fmaf(m0,m0,s2[0]); s2[1] = fmaf(m1,m1,s2[1]);
        s2[2] = fmaf(m2,m2,s2[2]); s2[3] = fmaf(m3,m3,s2[3]);
      }
      s1[0] += ts0; s1[1] += ts1; s1[2] += ts2; s1[3] += ts3;
      ts0 += __shfl_xor(ts0,16); ts0 += __shfl_xor(ts0,32);
      ts1 += __shfl_xor(ts1,16); ts1 += __shfl_xor(ts1,32);
      ts2 += __shfl_xor(ts2,16); ts2 += __shfl_xor(ts2,32);
      ts3 += __shfl_xor(ts3,16); ts3 += __shfl_xor(ts3,32);
      r0 += ts0; r1 += ts1; r2 += ts2; r3 += ts3;
    }
    float v = (kg==0) ? r0 : (kg==1) ? r1 : (kg==2) ? r2 : r3;
    u16 hiv = f2bf(v);
    aggs[(size_t)n*128 + lane]      = hiv;
    aggs[(size_t)n*128 + 64 + lane] = f2bf(v - bf2f(hiv));
  }
#pragma unroll
  for (int t = 0; t < 4; t++){
    atomicAdd(&bs[t*16+nn], s1[t]);
    atomicAdd(&bs[64+t*16+nn], s2[t]);
  }
  __syncthreads();
  if (tid < 128) atomicAdd(&stats[tid], bs[tid]);
}

// ---------------- MFMA message kernel v3: flat tile-list walk ----------------
// Hot loop has ZERO rp traffic and no loop-carried scalar-load chain: tile
// records come from a dense per-wave list; base is a running sum of rem.
// Depth-2 operand prefetch as in v2; numerics identical (same tile order).
__global__ void __launch_bounds__(256) k_msgmm3(
    const u16* __restrict__ hsp, const u16* __restrict__ eacsr,
    const int* __restrict__ rp, const int* __restrict__ perm,
    const u16* __restrict__ Wl, u16* __restrict__ aggs,
    float* __restrict__ stats, const int* __restrict__ wranges,
    const int* __restrict__ twoff, const int* __restrict__ tlist){
  __shared__ float bs[128];
  int tid = threadIdx.x;
  if (tid < 128) bs[tid] = 0.f;
  __syncthreads();
  int lane = tid & 63;
  int w = blockIdx.x*4 + (tid >> 6);
  int nn = lane & 15, kg = lane >> 4;
  bf16x8 B[3][4];
#pragma unroll
  for (int t = 0; t < 4; t++)
#pragma unroll
    for (int kb = 0; kb < 3; kb++)
      B[kb][t] = *(const bf16x8*)(Wl + (size_t)(t*16+nn)*96 + kb*32 + kg*8);
  U4BF ac; ac.u = make_uint4((kg==2)? 0x3f80u : 0u, 0u, 0u, 0u);
  float s1[4] = {0,0,0,0}, s2[4] = {0,0,0,0};

  int nBeg = wranges[w], nEnd = wranges[w+1];
  // pre-pass: zero rows of empty nodes (rare; main walk skips them)
  if (nBeg < nEnd){
    int pv = rp[nBeg];
    for (int m = nBeg; m < nEnd; m++){
      int nx = rp[m+1];
      if (nx == pv){
        aggs[(size_t)m*128 + lane] = 0;
        aggs[(size_t)m*128 + 64 + lane] = 0;
      }
      pv = nx;
    }
  }

  int tB = twoff[w], tE = twoff[w+1];
  if (tB < tE){
    int recA = tlist[tB];
    int baseA = rp[nBeg];                 // first tile's base (empties share rp)
    int recB = (tB+1 < tE) ? tlist[tB+1] : recA;
    int baseB = baseA + ((recA>>1)&15) + 1;
    // prologue loads for tile A
    U4BF fAA, fAB, fAC;
    {
      int pA = perm[baseA + nn];
      const uint4* hpA = (const uint4*)(hsp + (size_t)pA*128);
      fAA.u = hpA[kg]; fAB.u = hpA[4 + kg];
      if (kg < 2) fAC.u = *(const uint4*)(eacsr + ((size_t)baseA + nn)*16 + (size_t)kg*8);
      else fAC = ac;
    }
    int pB = perm[baseB + nn];
    float r0 = 0.f, r1 = 0.f, r2 = 0.f, r3 = 0.f;
    for (int i = tB; i < tE; i++){
      // prefetch tile i+2's record/perm (clamped; values dead past tail)
      int recC = (i+2 < tE) ? tlist[i+2] : recB;
      int baseC = baseB + ((recB>>1)&15) + 1;
      int pC = perm[baseC + nn];
      // load tile i+1 operands (overlap with MFMA of tile i)
      const uint4* hpB = (const uint4*)(hsp + (size_t)pB*128);
      U4BF fBA, fBB, fBC;
      fBA.u = hpB[kg]; fBB.u = hpB[4 + kg];
      if (kg < 2) fBC.u = *(const uint4*)(eacsr + ((size_t)baseB + nn)*16 + (size_t)kg*8);
      else fBC = ac;
      // MFMA on tile i
      f32x4 a0 = {0,0,0,0}, a1 = {0,0,0,0}, a2 = {0,0,0,0}, a3 = {0,0,0,0};
      a0 = __builtin_amdgcn_mfma_f32_16x16x32_bf16(fAA.v, B[0][0], a0, 0,0,0);
      a1 = __builtin_amdgcn_mfma_f32_16x16x32_bf16(fAA.v, B[0][1], a1, 0,0,0);
      a2 = __builtin_amdgcn_mfma_f32_16x16x32_bf16(fAA.v, B[0][2], a2, 0,0,0);
      a3 = __builtin_amdgcn_mfma_f32_16x16x32_bf16(fAA.v, B[0][3], a3, 0,0,0);
      a0 = __builtin_amdgcn_mfma_f32_16x16x32_bf16(fAB.v, B[1][0], a0, 0,0,0);
      a1 = __builtin_amdgcn_mfma_f32_16x16x32_bf16(fAB.v, B[1][1], a1, 0,0,0);
      a2 = __builtin_amdgcn_mfma_f32_16x16x32_bf16(fAB.v, B[1][2], a2, 0,0,0);
      a3 = __builtin_amdgcn_mfma_f32_16x16x32_bf16(fAB.v, B[1][3], a3, 0,0,0);
      a0 = __builtin_amdgcn_mfma_f32_16x16x32_bf16(fAC.v, B[2][0], a0, 0,0,0);
      a1 = __builtin_amdgcn_mfma_f32_16x16x32_bf16(fAC.v, B[2][1], a1, 0,0,0);
      a2 = __builtin_amdgcn_mfma_f32_16x16x32_bf16(fAC.v, B[2][2], a2, 0,0,0);
      a3 = __builtin_amdgcn_mfma_f32_16x16x32_bf16(fAC.v, B[2][3], a3, 0,0,0);
      // epilogue for tile i
      int rem = ((recA >> 1) & 15) + 1;
      int rowbase = kg*4;
      float ts0 = 0.f, ts1 = 0.f, ts2 = 0.f, ts3 = 0.f;
#pragma unroll
      for (int j = 0; j < 4; j++){
        bool valid = (rowbase + j) < rem;
        float m0 = fmaxf(a0[j], 0.f); m0 = valid ? m0 : 0.f;
        float m1 = fmaxf(a1[j], 0.f); m1 = valid ? m1 : 0.f;
        float m2 = fmaxf(a2[j], 0.f); m2 = valid ? m2 : 0.f;
        float m3 = fmaxf(a3[j], 0.f); m3 = valid ? m3 : 0.f;
        ts0 += m0; ts1 += m1; ts2 += m2; ts3 += m3;
        s2[0] = fmaf(m0,m0,s2[0]); s2[1] = fmaf(m1,m1,s2[1]);
        s2[2] = fmaf(m2,m2,s2[2]); s2[3] = fmaf(m3,m3,s2[3]);
      }
      s1[0] += ts0; s1[1] += ts1; s1[2] += ts2; s1[3] += ts3;
      r0 += ts0; r1 += ts1; r2 += ts2; r3 += ts3;
      if (recA & 1){                      // last tile of its node
        r0 += __shfl_xor(r0,16); r0 += __shfl_xor(r0,32);
        r1 += __shfl_xor(r1,16); r1 += __shfl_xor(r1,32);
        r2 += __shfl_xor(r2,16); r2 += __shfl_xor(r2,32);
        r3 += __shfl_xor(r3,16); r3 += __shfl_xor(r3,32);
        float v = (kg==0) ? r0 : (kg==1) ? r1 : (kg==2) ? r2 : r3;
        int node = recA >> 5;
        u16 hiv = f2bf(v);
        aggs[(size_t)node*128 + lane]      = hiv;
        aggs[(size_t)node*128 + 64 + lane] = f2bf(v - bf2f(hiv));
        r0 = r1 = r2 = r3 = 0.f;
      }
      // rotate pipeline
      recA = recB; baseA = baseB;
      fAA = fBA; fAB = fBB; fAC = fBC;
      recB = recC; baseB = baseC; pB = pC;
    }
  }
#pragma unroll
  for (int t = 0; t < 4; t++){
    atomicAdd(&bs[t*16+nn], s1[t]);
    atomicAdd(&bs[64+t*16+nn], s2[t]);
  }
  __syncthreads();
  if (tid < 128) atomicAdd(&stats[tid], bs[tid]);
}

// ---------------- BN finalize (self-zeroes stats) ----------------
__global__ void k_fin(float* __restrict__ stats, const void* __restrict__ gamma,
                      const void* __restrict__ beta, float* __restrict__ aff,
                      float cnt_inv, int goff, const int* __restrict__ flagp){
  int isbf = *flagp; int c = threadIdx.x;
  float mu  = stats[c]      * cnt_inv;
  float var = stats[64 + c] * cnt_inv - mu*mu;
  float rs  = rsqrtf(var + 1e-5f);
  float g = ldf(gamma, (size_t)goff + c, isbf);
  float b = ldf(beta,  (size_t)goff + c, isbf);
  aff[c]      = g*rs;
  aff[64 + c] = b - g*mu*rs;
  stats[c] = 0.f; stats[64 + c] = 0.f;
}

// ---------------- MFMA fused update, split-precision ----------------
// r15: REGULAR loads (NT removed) — hsp/aggs are freshly written, L3-resident;
// NT bypass forced HBM re-fetch (r12-measured mechanism) and left L3 cold for
// the next layer's msgmm gather.
#define UPD_TILES (N_NODES/16)
__global__ void __launch_bounds__(256) k_updmm(
    const u16* __restrict__ hsp, u16* __restrict__ aggs,
    const float* __restrict__ degf, const u16* __restrict__ Wupd,
    const float* __restrict__ biasv, const float* __restrict__ tvv,
    float* __restrict__ stats){
  __shared__ float bs[128];
  int tid = threadIdx.x;
  if (tid < 128) bs[tid] = 0.f;
  __syncthreads();
  int lane = tid & 63;
  int nn = lane & 15, kg = lane >> 4;
  int w = blockIdx.x*4 + (tid >> 6);
  int nwv = gridDim.x*4;
  bf16x8 B[6][4];
#pragma unroll
  for (int t = 0; t < 4; t++)
#pragma unroll
    for (int kb = 0; kb < 6; kb++)
      B[kb][t] = *(const bf16x8*)(Wupd + (size_t)(t*16+nn)*192 + kb*32 + kg*8);
  float bc[4], tc[4];
#pragma unroll
  for (int t = 0; t < 4; t++){ bc[t] = biasv[t*16+nn]; tc[t] = tvv[t*16+nn]; }
  float s1[4] = {0,0,0,0}, s2[4] = {0,0,0,0};
  for (int tile = w; tile < UPD_TILES; tile += nwv){
    int n0 = tile*16;
    int r = n0 + nn;
    const uint4* hp = (const uint4*)hsp;
    const uint4* ap = (const uint4*)aggs;
    U4BF hh0, hh1, hl0, hl1, ah0, ah1, al0, al1;
    hh0.u = hp[(size_t)r*16 + kg];       hh1.u = hp[(size_t)r*16 + 4 + kg];
    hl0.u = hp[(size_t)r*16 + 8 + kg];   hl1.u = hp[(size_t)r*16 + 12 + kg];
    ah0.u = ap[(size_t)r*16 + kg];       ah1.u = ap[(size_t)r*16 + 4 + kg];
    al0.u = ap[(size_t)r*16 + 8 + kg];   al1.u = ap[(size_t)r*16 + 12 + kg];
    float dg[4];
#pragma unroll
    for (int j = 0; j < 4; j++) dg[j] = degf[n0 + kg*4 + j];
    f32x4 a0 = {0,0,0,0}, a1 = {0,0,0,0}, a2 = {0,0,0,0}, a3 = {0,0,0,0};
#define MF(F,KB) \
    a0 = __builtin_amdgcn_mfma_f32_16x16x32_bf16(F.v, B[KB][0], a0, 0,0,0); \
    a1 = __builtin_amdgcn_mfma_f32_16x16x32_bf16(F.v, B[KB][1], a1, 0,0,0); \
    a2 = __builtin_amdgcn_mfma_f32_16x16x32_bf16(F.v, B[KB][2], a2, 0,0,0); \
    a3 = __builtin_amdgcn_mfma_f32_16x16x32_bf16(F.v, B[KB][3], a3, 0,0,0);
    MF(hh0,0) MF(hh1,1) MF(hl0,0) MF(hl1,1)
    MF(ah0,2) MF(ah1,3) MF(ah0,4) MF(ah1,5)
    MF(al0,2) MF(al1,3)
#undef MF
#pragma unroll
    for (int j = 0; j < 4; j++){
      int n = n0 + kg*4 + j;
      float m0 = fmaxf(fmaf(tc[0], dg[j], a0[j] + bc[0]), 0.f);
      float m1 = fmaxf(fmaf(tc[1], dg[j], a1[j] + bc[1]), 0.f);
      float m2 = fmaxf(fmaf(tc[2], dg[j], a2[j] + bc[2]), 0.f);
      float m3 = fmaxf(fmaf(tc[3], dg[j], a3[j] + bc[3]), 0.f);
      s1[0] += m0; s1[1] += m1; s1[2] += m2; s1[3] += m3;
      s2[0] = fmaf(m0,m0,s2[0]); s2[1] = fmaf(m1,m1,s2[1]);
      s2[2] = fmaf(m2,m2,s2[2]); s2[3] = fmaf(m3,m3,s2[3]);
      u16* hw = aggs + (size_t)n*128;
      u16 q0 = f2bf(m0), q1 = f2bf(m1), q2 = f2bf(m2), q3 = f2bf(m3);
      hw[     nn] = q0;  hw[64 +      nn] = f2bf(m0 - bf2f(q0));
      hw[16 + nn] = q1;  hw[64 + 16 + nn] = f2bf(m1 - bf2f(q1));
      hw[32 + nn] = q2;  hw[64 + 32 + nn] = f2bf(m2 - bf2f(q2));
      hw[48 + nn] = q3;  hw[64 + 48 + nn] = f2bf(m3 - bf2f(q3));
    }
  }
#pragma unroll
  for (int t = 0; t < 4; t++){
    atomicAdd(&bs[t*16+nn], s1[t]);
    atomicAdd(&bs[64+t*16+nn], s2[t]);
  }
  __syncthreads();
  if (tid < 128) atomicAdd(&stats[tid], bs[tid]);
}

// ---------------- global add pool over PRE-BN h with affine applied ----------
__global__ void k_pool(const u16* __restrict__ hsp, const int* __restrict__ batch,
                       const float* __restrict__ aff, float* __restrict__ g){
  int lane = threadIdx.x & 63;
  int gw = (blockIdx.x*blockDim.x + threadIdx.x) >> 6;
  int nw = (gridDim.x*blockDim.x) >> 6;
  float s = aff[lane], t = aff[64 + lane];
  int chunk = (N_NODES + nw - 1) / nw;
  int n0 = gw*chunk;
  int n1 = n0 + chunk; if (n1 > N_NODES) n1 = N_NODES;
  int cur = -1; float acc = 0.f, cnt = 0.f;
  for (int n = n0; n < n1; n++){
    int b = batch[n];
    float v = bf2f(hsp[(size_t)n*128 + lane]) + bf2f(hsp[(size_t)n*128 + 64 + lane]);
    if (b != cur){
      if (cur >= 0) atomicAdd(&g[(size_t)cur*64 + lane], fmaf(s, acc, t*cnt));
      cur = b; acc = v; cnt = 1.f;
    } else { acc += v; cnt += 1.f; }
  }
  if (cur >= 0) atomicAdd(&g[(size_t)cur*64 + lane], fmaf(s, acc, t*cnt));
}

// ---------------- readout ----------------
__global__ void k_read(const float* __restrict__ g, const void* __restrict__ r1W,
                       const void* __restrict__ r1b, const void* __restrict__ r2W,
                       const void* __restrict__ r2b, void* __restrict__ out,
                       const int* __restrict__ flagp){
  int isbf = *flagp;
  int lane = threadIdx.x;
  int gr = blockIdx.x;
  float w[64];
#pragma unroll
  for (int k = 0; k < 64; k++) w[k] = ldf(r1W, (size_t)k*64 + lane, isbf);
  float acc = ldf(r1b, lane, isbf);
  const float4* grow = (const float4*)(g + (size_t)gr*64);
#pragma unroll
  for (int q = 0; q < 16; q++){
    float4 a = grow[q];
    acc = fmaf(a.x, w[4*q+0], acc); acc = fmaf(a.y, w[4*q+1], acc);
    acc = fmaf(a.z, w[4*q+2], acc); acc = fmaf(a.w, w[4*q+3], acc);
  }
  float hid = fmaxf(acc, 0.f);
  float p = hid * ldf(r2W, lane, isbf);
  for (int o = 32; o; o >>= 1) p += __shfl_xor(p, o);
  if (lane == 0){
    float v = p + ldf(r2b, 0, isbf);
    if (isbf) ((__hip_bfloat16*)out)[gr] = __float2bfloat16(v);
    else      ((float*)out)[gr] = v;
  }
}

extern "C" void kernel_launch(void* const* d_in, const int* in_sizes, int n_in,
                              void* d_out, int out_size, void* d_ws, size_t ws_size,
                              hipStream_t stream){
  const void* x    = d_in[0];
  const void* ea   = d_in[1];
  const int*  ei   = (const int*)d_in[2];
  const int*  bt   = (const int*)d_in[3];
  const void* nW   = d_in[4];  const void* nb  = d_in[5];
  const void* eW   = d_in[6];  const void* eb  = d_in[7];
  const void* mW   = d_in[8];  const void* mb  = d_in[9];
  const void* mg   = d_in[10]; const void* mbe = d_in[11];
  const void* uW   = d_in[12]; const void* ub  = d_in[13];
  const void* ug   = d_in[14]; const void* ube = d_in[15];
  const void* r1W  = d_in[16]; const void* r1b = d_in[17];
  const void* r2W  = d_in[18]; const void* r2b = d_in[19];

  // big path needs 27,908,684 floats = 111,634,736 bytes
  const size_t NEED_BIG = 111634736ull;
  const bool big = (ws_size >= NEED_BIG);

  float* ws = (float*)d_ws;
  size_t off = 0;
  auto alloc = [&](size_t n){ float* p = ws + off; off += n; return p; };

  u16*   hsp   = (u16*)alloc(6400000);
  u16*   aggs  = (u16*)alloc(6400000);
  u16*   eacsr = nullptr; int* perm = nullptr; int* perm2 = nullptr;
  int*   tcnt = nullptr; int* twoff = nullptr; int* tlist = nullptr;
  if (big){
    eacsr = (u16*)alloc(12800384);          // (E+48) rows x 16 u16
    perm  = (int*)alloc(1600048);           // E+48 ints
  } else {
    perm2 = (int*)alloc(3200000);           // E int2
  }
  float* degf   = alloc(100000);
  float* zero0  = ws + off;                 // memset region start
  int*   deg_i  = (int*)alloc(100000);
  float* g      = alloc(64000);
  float* mstats = alloc(128);
  float* ustats = alloc(128);
  size_t zeroN  = (size_t)((ws + off) - zero0);   // 164,256 floats
  float* maff   = alloc(128);
  float* haff   = alloc(128);
  int*   flag   = (int*)alloc(16);
  u16*   Weff   = (u16*)alloc(9216);        // base msg weights (3 layers)
  u16*   Wfold  = (u16*)alloc(3072);        // per-layer folded msg weights
  u16*   Wupd   = (u16*)alloc(6144);
  float* biasm  = alloc(192);               // f32 base msg bias (3 layers)
  float* biasv  = alloc(64);
  float* tvv    = alloc(64);
  int*   row_ptr= (int*)alloc(100001);
  int*   cursor = (int*)alloc(100000);
  int*   bsum   = (int*)alloc(196);
  int*   boff   = (int*)alloc(196);
  int*   wrng   = (int*)alloc(8194);        // wave ranges (MM_WAVES+1)
  if (big){
    tcnt  = (int*)alloc(8192);
    twoff = (int*)alloc(8193);
    tlist = (int*)alloc(200000);            // <= E/16 + N tiles
  }

  const int MM_BLOCKS = 2048;
  const int MM_WAVES  = MM_BLOCKS * 4;
  const int UPD_BLOCKS = 782;

  k_detect<<<1, 64, 0, stream>>>((const u32*)x, flag);
  hipMemsetAsync(zero0, 0, zeroN*sizeof(float), stream);
  k_idaff<<<1, 64, 0, stream>>>(haff);
  k_prep<<<3, 64, 0, stream>>>(eW, eb, mW, mb, Weff, biasm, flag);
  k_node_emb<<<256, 256, 0, stream>>>(x, nW, nb, hsp, flag);
  k_deg<<<512, 256, 0, stream>>>(ei, deg_i);
  k_scan1<<<196, 256, 0, stream>>>(deg_i, bsum);
  k_scan2<<<1, 256, 0, stream>>>(bsum, boff, row_ptr);
  k_scan3<<<196, 256, 0, stream>>>(deg_i, boff, row_ptr, cursor, degf);
  if (big){
    k_ranges<<<33, 256, 0, stream>>>(row_ptr, wrng, MM_WAVES);
    k_tcnt<<<32, 256, 0, stream>>>(row_ptr, wrng, tcnt, MM_WAVES);
    k_tscan<<<1, 256, 0, stream>>>(tcnt, twoff, MM_WAVES);
    k_tfill<<<32, 256, 0, stream>>>(row_ptr, wrng, twoff, tlist, MM_WAVES);
    k_scatter2<<<512, 256, 0, stream>>>(ei, cursor, perm, eacsr, ea, flag);
  } else {
    k_scatter<<<512, 256, 0, stream>>>(ei, cursor, perm2);
  }

  u16* H = hsp;   // current h (layer 0: embedding; l>0: pre-BN relu(u), haff pending)
  u16* G = aggs;  // scratch: msg agg, then overwritten by pre-BN relu(u)
  for (int l = 0; l < 3; l++){
    k_fold<<<1, 64, 0, stream>>>(mW, Weff, biasm, haff, Wfold, flag, l);
    if (big)
      k_msgmm3<<<MM_BLOCKS, 256, 0, stream>>>(H, eacsr, row_ptr, perm, Wfold,
                                              G, mstats, wrng, twoff, tlist);
    else
      k_msgmm<<<MM_BLOCKS, 256, 0, stream>>>(H, ea, row_ptr, perm2, Wfold,
                                             G, mstats, flag, MM_WAVES);
    k_fin<<<1, 64, 0, stream>>>(mstats, mg, mbe, maff, 1.0f/(float)N_EDGES, l*64, flag);
    k_updprep<<<1, 64, 0, stream>>>(uW, ub, maff, haff, Wupd, biasv, tvv, flag, l);
    k_updmm<<<UPD_BLOCKS, 256, 0, stream>>>(H, G, degf, Wupd, biasv, tvv, ustats);
    k_fin<<<1, 64, 0, stream>>>(ustats, ug, ube, haff, 1.0f/(float)N_NODES, l*64, flag);
    u16* tmp = H; H = G; G = tmp;
  }

  k_pool<<<128, 256, 0, stream>>>(H, bt, haff, g);
  k_read<<<NUM_GRAPHS, 64, 0, stream>>>(g, r1W, r1b, r2W, r2b, d_out, flag);
}